// Round 3
// baseline (2879.038 us; speedup 1.0000x reference)
//
#include <hip/hip_runtime.h>

typedef __attribute__((ext_vector_type(4))) int i32x4;

#define N_NODES   4000000
#define N_EDGES   12000000
#define N_GRAPHS  1000000

// ws layout:
//   [0,        16 MB) : deg as u32, overwritten in-place with dinv as f32
//   [16 MB,    32 MB) : acc4 f32 [N_GRAPHS][4]  (edge-scatter accumulator)
//   [32 MB, +640 B)   : folded weights: Wg1T[32][4] (=W_gcn@W1[4:36] transposed), b1p[32]

__global__ __launch_bounds__(256) void fold_kernel(
    const float* __restrict__ Wgcn, const float* __restrict__ bgcn,
    const float* __restrict__ W1, const float* __restrict__ b1,
    float* __restrict__ fold) {
  int t = threadIdx.x;
  if (t < 128) {
    int j = t >> 2, c = t & 3;
    float s = 0.f;
    for (int k = 0; k < 32; ++k) s += Wgcn[c * 32 + k] * W1[(4 + k) * 32 + j];
    fold[j * 4 + c] = s;                    // Wg1T[j][c]
  }
  if (t < 32) {
    float s = 0.f;
    for (int k = 0; k < 32; ++k) s += bgcn[k] * W1[(4 + k) * 32 + t];
    fold[128 + t] = b1[t] + 4.0f * s;       // b1p[j]
  }
}

__global__ __launch_bounds__(256) void deg_kernel(
    const i32x4* __restrict__ dst4, unsigned* __restrict__ deg) {
  int stride = gridDim.x * blockDim.x;
  for (int e = blockIdx.x * blockDim.x + threadIdx.x; e < N_EDGES / 4; e += stride) {
    i32x4 d = __builtin_nontemporal_load(dst4 + e);
    atomicAdd(&deg[d.x], 1u);
    atomicAdd(&deg[d.y], 1u);
    atomicAdd(&deg[d.z], 1u);
    atomicAdd(&deg[d.w], 1u);
  }
}

__global__ __launch_bounds__(256) void dinv_kernel(unsigned* __restrict__ degdinv) {
  int i = blockIdx.x * blockDim.x + threadIdx.x;
  if (i < N_NODES) {
    float dv = rsqrtf((float)(degdinv[i] + 1u));   // +1 = self loop
    reinterpret_cast<float*>(degdinv)[i] = dv;
  }
}

__global__ __launch_bounds__(256) void scatter_kernel(
    const i32x4* __restrict__ src4, const i32x4* __restrict__ dst4,
    const float* __restrict__ dinv, const float4* __restrict__ state4,
    float* __restrict__ acc) {
  int stride = gridDim.x * blockDim.x;
  for (int e = blockIdx.x * blockDim.x + threadIdx.x; e < N_EDGES / 4; e += stride) {
    i32x4 s4 = __builtin_nontemporal_load(src4 + e);
    i32x4 d4 = __builtin_nontemporal_load(dst4 + e);
#pragma unroll
    for (int u = 0; u < 4; ++u) {
      int s = (u == 0) ? s4.x : (u == 1) ? s4.y : (u == 2) ? s4.z : s4.w;
      int d = (u == 0) ? d4.x : (u == 1) ? d4.y : (u == 2) ? d4.z : d4.w;
      float w = dinv[s] * dinv[d];
      float4 st = state4[s];
      float* base = acc + (size_t)(d >> 2) * 4;
      atomicAdd(base + 0, w * st.x);
      atomicAdd(base + 1, w * st.y);
      atomicAdd(base + 2, w * st.z);
      atomicAdd(base + 3, w * st.w);
    }
  }
}

__global__ __launch_bounds__(256) void final_kernel(
    const float4* __restrict__ state4, const float4* __restrict__ dinv4,
    const float4* __restrict__ acc4, const float* __restrict__ W1,
    const float4* __restrict__ foldv, const float* __restrict__ fold,
    const float* __restrict__ W2, const float* __restrict__ b2,
    float* __restrict__ out) {
  __shared__ float4 w1aT[32];
  __shared__ float4 wg1T[32];
  __shared__ float b1p[32];
  __shared__ float w2s[32];
  int t = threadIdx.x;
  if (t < 32) {
    w1aT[t] = make_float4(W1[t], W1[32 + t], W1[64 + t], W1[96 + t]);
    wg1T[t] = foldv[t];
    b1p[t]  = fold[128 + t];
    w2s[t]  = W2[t];
  }
  __syncthreads();
  int b = blockIdx.x * blockDim.x + t;
  if (b >= N_GRAPHS) return;
  float4 s0 = state4[4 * b + 0], s1 = state4[4 * b + 1];
  float4 s2 = state4[4 * b + 2], s3 = state4[4 * b + 3];
  float4 dv = dinv4[b];
  float4 a  = acc4[b];
  float q0 = dv.x * dv.x, q1 = dv.y * dv.y, q2 = dv.z * dv.z, q3 = dv.w * dv.w;
  a.x += q0 * s0.x + q1 * s1.x + q2 * s2.x + q3 * s3.x;
  a.y += q0 * s0.y + q1 * s1.y + q2 * s2.y + q3 * s3.y;
  a.z += q0 * s0.z + q1 * s1.z + q2 * s2.z + q3 * s3.z;
  a.w += q0 * s0.w + q1 * s1.w + q2 * s2.w + q3 * s3.w;
  float4 vs;
  vs.x = s0.x + s1.x + s2.x + s3.x;
  vs.y = s0.y + s1.y + s2.y + s3.y;
  vs.z = s0.z + s1.z + s2.z + s3.z;
  vs.w = s0.w + s1.w + s2.w + s3.w;
  float accum = b2[0];
#pragma unroll
  for (int j = 0; j < 32; ++j) {
    float4 wa = w1aT[j], wg = wg1T[j];
    float h = b1p[j]
            + vs.x * wa.x + vs.y * wa.y + vs.z * wa.z + vs.w * wa.w
            + a.x * wg.x + a.y * wg.y + a.z * wg.z + a.w * wg.w;
    accum += fmaxf(h, 0.f) * w2s[j];
  }
  out[b] = accum;
}

extern "C" void kernel_launch(void* const* d_in, const int* in_sizes, int n_in,
                              void* d_out, int out_size, void* d_ws, size_t ws_size,
                              hipStream_t stream) {
  const float* state = (const float*)d_in[0];
  const int*   ei    = (const int*)d_in[1];   // int32: [2][N_EDGES]
  const float* Wgcn  = (const float*)d_in[2];
  const float* bgcn  = (const float*)d_in[3];
  const float* W1    = (const float*)d_in[4];
  const float* b1    = (const float*)d_in[5];
  const float* W2    = (const float*)d_in[6];
  const float* b2    = (const float*)d_in[7];
  float* out = (float*)d_out;

  char* ws = (char*)d_ws;
  unsigned* deg = (unsigned*)ws;                           // 16 MB
  float* acc    = (float*)(ws + (size_t)16 * 1024 * 1024); // 16 MB
  float* fold   = (float*)(ws + (size_t)32 * 1024 * 1024); // 640 B

  (void)hipMemsetAsync(d_ws, 0, (size_t)32 * 1024 * 1024 + 1024, stream);
  fold_kernel<<<1, 128, 0, stream>>>(Wgcn, bgcn, W1, b1, fold);
  deg_kernel<<<4096, 256, 0, stream>>>((const i32x4*)(ei + N_EDGES), deg);
  dinv_kernel<<<(N_NODES + 255) / 256, 256, 0, stream>>>(deg);
  scatter_kernel<<<8192, 256, 0, stream>>>(
      (const i32x4*)ei, (const i32x4*)(ei + N_EDGES),
      (const float*)deg, (const float4*)state, acc);
  final_kernel<<<(N_GRAPHS + 255) / 256, 256, 0, stream>>>(
      (const float4*)state, (const float4*)deg, (const float4*)acc,
      W1, (const float4*)fold, fold, W2, b2, out);
}

// Round 4
// 1840.663 us; speedup vs baseline: 1.5641x; 1.5641x over previous
//
#include <hip/hip_runtime.h>

typedef __attribute__((ext_vector_type(4))) int i32x4;
typedef __attribute__((ext_vector_type(4))) unsigned u32x4;

#define N_NODES   4000000
#define N_EDGES   12000000
#define N_GRAPHS  1000000
#define GPB       1024   // graphs per scan block (256 threads x 4)
#define NSCANBLK  1024   // covers 1,048,576 >= N_GRAPHS (guarded)

// ---------------- shared small kernels ----------------

__global__ __launch_bounds__(256) void fold_kernel(
    const float* __restrict__ Wgcn, const float* __restrict__ bgcn,
    const float* __restrict__ W1, const float* __restrict__ b1,
    float* __restrict__ fold) {
  int t = threadIdx.x;
  if (t < 128) {
    int j = t >> 2, c = t & 3;
    float s = 0.f;
    for (int k = 0; k < 32; ++k) s += Wgcn[c * 32 + k] * W1[(4 + k) * 32 + j];
    fold[j * 4 + c] = s;                    // Wg1T[j][c]
  }
  if (t < 32) {
    float s = 0.f;
    for (int k = 0; k < 32; ++k) s += bgcn[k] * W1[(4 + k) * 32 + t];
    fold[128 + t] = b1[t] + 4.0f * s;       // b1p[j]
  }
}

__global__ __launch_bounds__(256) void deg_kernel(
    const i32x4* __restrict__ dst4, unsigned* __restrict__ deg) {
  int stride = gridDim.x * blockDim.x;
  for (int e = blockIdx.x * blockDim.x + threadIdx.x; e < N_EDGES / 4; e += stride) {
    i32x4 d = __builtin_nontemporal_load(dst4 + e);
    atomicAdd(&deg[d.x], 1u);
    atomicAdd(&deg[d.y], 1u);
    atomicAdd(&deg[d.z], 1u);
    atomicAdd(&deg[d.w], 1u);
  }
}

// ---------------- sort path ----------------

__global__ __launch_bounds__(256) void scan1_kernel(
    const unsigned* __restrict__ deg, unsigned* __restrict__ blocksum) {
  int t = threadIdx.x;
  int gb = blockIdx.x * GPB + t * 4;
  unsigned s = 0;
#pragma unroll
  for (int i = 0; i < 4; ++i) {
    int g = gb + i;
    if (g < N_GRAPHS) {
      u32x4 v = ((const u32x4*)deg)[g];
      s += v.x + v.y + v.z + v.w;
    }
  }
  __shared__ unsigned red[256];
  red[t] = s; __syncthreads();
  for (int off = 128; off > 0; off >>= 1) {
    if (t < off) red[t] += red[t + off];
    __syncthreads();
  }
  if (t == 0) blocksum[blockIdx.x] = red[0];
}

__global__ __launch_bounds__(256) void scan2_kernel(unsigned* __restrict__ blocksum) {
  // single block: exclusive scan of NSCANBLK entries in place
  int t = threadIdx.x;
  u32x4 v = ((const u32x4*)blocksum)[t];
  unsigned s1 = v.x + v.y, s2 = s1 + v.z, s3 = s2 + v.w;
  __shared__ unsigned tsum[256];
  tsum[t] = s3; __syncthreads();
  for (int off = 1; off < 256; off <<= 1) {
    unsigned add = (t >= off) ? tsum[t - off] : 0u;
    __syncthreads();
    tsum[t] += add;
    __syncthreads();
  }
  unsigned base = t ? tsum[t - 1] : 0u;
  u32x4 o; o.x = base; o.y = base + v.x; o.z = base + s1; o.w = base + s2;
  ((u32x4*)blocksum)[t] = o;
}

__global__ __launch_bounds__(256) void scan3_kernel(
    const unsigned* __restrict__ deg, const unsigned* __restrict__ blocksum,
    unsigned* __restrict__ cursor) {
  int t = threadIdx.x;
  int gb = blockIdx.x * GPB + t * 4;
  unsigned c[4];
#pragma unroll
  for (int i = 0; i < 4; ++i) {
    int g = gb + i;
    if (g < N_GRAPHS) {
      u32x4 v = ((const u32x4*)deg)[g];
      c[i] = v.x + v.y + v.z + v.w;
    } else c[i] = 0;
  }
  unsigned s3 = c[0] + c[1] + c[2] + c[3];
  __shared__ unsigned tsum[256];
  tsum[t] = s3; __syncthreads();
  for (int off = 1; off < 256; off <<= 1) {
    unsigned add = (t >= off) ? tsum[t - off] : 0u;
    __syncthreads();
    tsum[t] += add;
    __syncthreads();
  }
  unsigned base = blocksum[blockIdx.x] + (t ? tsum[t - 1] : 0u);
  if (gb < N_GRAPHS) {
    u32x4 o; o.x = base; o.y = base + c[0]; o.z = base + c[0] + c[1];
    o.w = base + c[0] + c[1] + c[2];
    // gb is a multiple of 4; up to 1M-4 so full vector is in range when gb+3<N_GRAPHS
    ((u32x4*)cursor)[gb >> 2] = o;
  }
}

__global__ __launch_bounds__(256) void dinv_dsi_kernel(
    unsigned* __restrict__ degdinv, const float4* __restrict__ state4,
    float4* __restrict__ dsi4, int use_dsi) {
  int i = blockIdx.x * blockDim.x + threadIdx.x;
  if (i < N_NODES) {
    float dv = rsqrtf((float)(degdinv[i] + 1u));   // +1 = self loop
    reinterpret_cast<float*>(degdinv)[i] = dv;
    if (use_dsi) {
      float4 s = state4[i];
      dsi4[i] = make_float4(dv * s.x, dv * s.y, dv * s.z, dv * s.w);
    }
  }
}

__global__ __launch_bounds__(256) void place_kernel(
    const i32x4* __restrict__ src4, const i32x4* __restrict__ dst4,
    unsigned* __restrict__ cursor, unsigned* __restrict__ recs) {
  int stride = gridDim.x * blockDim.x;
  for (int e = blockIdx.x * blockDim.x + threadIdx.x; e < N_EDGES / 4; e += stride) {
    i32x4 s4 = __builtin_nontemporal_load(src4 + e);
    i32x4 d4 = __builtin_nontemporal_load(dst4 + e);
#pragma unroll
    for (int u = 0; u < 4; ++u) {
      int s = (u == 0) ? s4.x : (u == 1) ? s4.y : (u == 2) ? s4.z : s4.w;
      int d = (u == 0) ? d4.x : (u == 1) ? d4.y : (u == 2) ? d4.z : d4.w;
      unsigned p = atomicAdd(&cursor[d >> 2], 1u);
      __builtin_nontemporal_store(((unsigned)s << 2) | (unsigned)(d & 3), &recs[p]);
    }
  }
}

template <bool DSI>
__global__ __launch_bounds__(256) void reduce_kernel(
    const unsigned* __restrict__ cursor, const unsigned* __restrict__ recs,
    const float* __restrict__ dinv, const float4* __restrict__ dsi4,
    const float4* __restrict__ state4,
    const float* __restrict__ W1, const float* __restrict__ fold,
    const float* __restrict__ W2, const float* __restrict__ b2,
    float* __restrict__ out) {
  __shared__ float4 w1aT[32];
  __shared__ float4 wg1T[32];
  __shared__ float b1p[32];
  __shared__ float w2s[32];
  int t = threadIdx.x;
  if (t < 32) {
    w1aT[t] = make_float4(W1[t], W1[32 + t], W1[64 + t], W1[96 + t]);
    wg1T[t] = ((const float4*)fold)[t];
    b1p[t]  = fold[128 + t];
    w2s[t]  = W2[t];
  }
  __syncthreads();
  int g = blockIdx.x * blockDim.x + t;
  if (g >= N_GRAPHS) return;
  unsigned start = g ? cursor[g - 1] : 0u;
  unsigned end   = cursor[g];
  float4 dv = ((const float4*)dinv)[g];
  float4 a = make_float4(0.f, 0.f, 0.f, 0.f);
  for (unsigned p = start; p < end; ++p) {
    unsigned rec = recs[p];
    unsigned s = rec >> 2;
    unsigned r = rec & 3u;
    float wd = (r == 0) ? dv.x : (r == 1) ? dv.y : (r == 2) ? dv.z : dv.w;
    if (DSI) {
      float4 m = dsi4[s];
      a.x += wd * m.x; a.y += wd * m.y; a.z += wd * m.z; a.w += wd * m.w;
    } else {
      float w = wd * dinv[s];
      float4 st = state4[s];
      a.x += w * st.x; a.y += w * st.y; a.z += w * st.z; a.w += w * st.w;
    }
  }
  float4 s0 = state4[4 * g + 0], s1 = state4[4 * g + 1];
  float4 s2 = state4[4 * g + 2], s3 = state4[4 * g + 3];
  float q0 = dv.x * dv.x, q1 = dv.y * dv.y, q2 = dv.z * dv.z, q3 = dv.w * dv.w;
  a.x += q0 * s0.x + q1 * s1.x + q2 * s2.x + q3 * s3.x;
  a.y += q0 * s0.y + q1 * s1.y + q2 * s2.y + q3 * s3.y;
  a.z += q0 * s0.z + q1 * s1.z + q2 * s2.z + q3 * s3.z;
  a.w += q0 * s0.w + q1 * s1.w + q2 * s2.w + q3 * s3.w;
  float4 vs;
  vs.x = s0.x + s1.x + s2.x + s3.x;
  vs.y = s0.y + s1.y + s2.y + s3.y;
  vs.z = s0.z + s1.z + s2.z + s3.z;
  vs.w = s0.w + s1.w + s2.w + s3.w;
  float accum = b2[0];
#pragma unroll
  for (int j = 0; j < 32; ++j) {
    float4 wa = w1aT[j], wg = wg1T[j];
    float h = b1p[j]
            + vs.x * wa.x + vs.y * wa.y + vs.z * wa.z + vs.w * wa.w
            + a.x * wg.x + a.y * wg.y + a.z * wg.z + a.w * wg.w;
    accum += fmaxf(h, 0.f) * w2s[j];
  }
  out[g] = accum;
}

// ---------------- fallback (round-3) kernels ----------------

__global__ __launch_bounds__(256) void dinv_kernel(unsigned* __restrict__ degdinv) {
  int i = blockIdx.x * blockDim.x + threadIdx.x;
  if (i < N_NODES) {
    float dv = rsqrtf((float)(degdinv[i] + 1u));
    reinterpret_cast<float*>(degdinv)[i] = dv;
  }
}

__global__ __launch_bounds__(256) void scatter_kernel(
    const i32x4* __restrict__ src4, const i32x4* __restrict__ dst4,
    const float* __restrict__ dinv, const float4* __restrict__ state4,
    float* __restrict__ acc) {
  int stride = gridDim.x * blockDim.x;
  for (int e = blockIdx.x * blockDim.x + threadIdx.x; e < N_EDGES / 4; e += stride) {
    i32x4 s4 = __builtin_nontemporal_load(src4 + e);
    i32x4 d4 = __builtin_nontemporal_load(dst4 + e);
#pragma unroll
    for (int u = 0; u < 4; ++u) {
      int s = (u == 0) ? s4.x : (u == 1) ? s4.y : (u == 2) ? s4.z : s4.w;
      int d = (u == 0) ? d4.x : (u == 1) ? d4.y : (u == 2) ? d4.z : d4.w;
      float w = dinv[s] * dinv[d];
      float4 st = state4[s];
      float* base = acc + (size_t)(d >> 2) * 4;
      atomicAdd(base + 0, w * st.x);
      atomicAdd(base + 1, w * st.y);
      atomicAdd(base + 2, w * st.z);
      atomicAdd(base + 3, w * st.w);
    }
  }
}

__global__ __launch_bounds__(256) void final_kernel(
    const float4* __restrict__ state4, const float4* __restrict__ dinv4,
    const float4* __restrict__ acc4, const float* __restrict__ W1,
    const float* __restrict__ fold, const float* __restrict__ W2,
    const float* __restrict__ b2, float* __restrict__ out) {
  __shared__ float4 w1aT[32];
  __shared__ float4 wg1T[32];
  __shared__ float b1p[32];
  __shared__ float w2s[32];
  int t = threadIdx.x;
  if (t < 32) {
    w1aT[t] = make_float4(W1[t], W1[32 + t], W1[64 + t], W1[96 + t]);
    wg1T[t] = ((const float4*)fold)[t];
    b1p[t]  = fold[128 + t];
    w2s[t]  = W2[t];
  }
  __syncthreads();
  int b = blockIdx.x * blockDim.x + t;
  if (b >= N_GRAPHS) return;
  float4 s0 = state4[4 * b + 0], s1 = state4[4 * b + 1];
  float4 s2 = state4[4 * b + 2], s3 = state4[4 * b + 3];
  float4 dv = dinv4[b];
  float4 a  = acc4[b];
  float q0 = dv.x * dv.x, q1 = dv.y * dv.y, q2 = dv.z * dv.z, q3 = dv.w * dv.w;
  a.x += q0 * s0.x + q1 * s1.x + q2 * s2.x + q3 * s3.x;
  a.y += q0 * s0.y + q1 * s1.y + q2 * s2.y + q3 * s3.y;
  a.z += q0 * s0.z + q1 * s1.z + q2 * s2.z + q3 * s3.z;
  a.w += q0 * s0.w + q1 * s1.w + q2 * s2.w + q3 * s3.w;
  float4 vs;
  vs.x = s0.x + s1.x + s2.x + s3.x;
  vs.y = s0.y + s1.y + s2.y + s3.y;
  vs.z = s0.z + s1.z + s2.z + s3.z;
  vs.w = s0.w + s1.w + s2.w + s3.w;
  float accum = b2[0];
#pragma unroll
  for (int j = 0; j < 32; ++j) {
    float4 wa = w1aT[j], wg = wg1T[j];
    float h = b1p[j]
            + vs.x * wa.x + vs.y * wa.y + vs.z * wa.z + vs.w * wa.w
            + a.x * wg.x + a.y * wg.y + a.z * wg.z + a.w * wg.w;
    accum += fmaxf(h, 0.f) * w2s[j];
  }
  out[b] = accum;
}

// ---------------- launch ----------------

extern "C" void kernel_launch(void* const* d_in, const int* in_sizes, int n_in,
                              void* d_out, int out_size, void* d_ws, size_t ws_size,
                              hipStream_t stream) {
  const float* state = (const float*)d_in[0];
  const int*   ei    = (const int*)d_in[1];   // int32: [2][N_EDGES]
  const float* Wgcn  = (const float*)d_in[2];
  const float* bgcn  = (const float*)d_in[3];
  const float* W1    = (const float*)d_in[4];
  const float* b1    = (const float*)d_in[5];
  const float* W2    = (const float*)d_in[6];
  const float* b2    = (const float*)d_in[7];
  float* out = (float*)d_out;

  char* ws = (char*)d_ws;
  const size_t MB = 1024u * 1024u;

  const size_t need_dsi   = 137 * MB;
  const size_t need_nodsi = 74 * MB;

  if (ws_size >= need_nodsi) {
    // sort-path layout:
    //   [0,16MB)      deg u32 -> dinv f32 in place
    //   [16,20MB)     cursor u32[2^20] (exclusive offsets -> bucket ends after place)
    //   [20MB,+4KB)   blocksum u32[1024]
    //   [20MB+8KB,+640B) fold
    //   no-dsi: recs at [24,72MB)
    //   dsi:    dsi4 at [24,88MB), recs at [88,136MB)
    bool use_dsi = (ws_size >= need_dsi);
    unsigned* deg      = (unsigned*)ws;
    unsigned* cursor   = (unsigned*)(ws + 16 * MB);
    unsigned* blocksum = (unsigned*)(ws + 20 * MB);
    float*    fold     = (float*)(ws + 20 * MB + 8192);
    float4*   dsi4     = (float4*)(ws + 24 * MB);
    unsigned* recs     = (unsigned*)(ws + (use_dsi ? 88 * MB : 24 * MB));

    (void)hipMemsetAsync(deg, 0, 16 * MB, stream);
    fold_kernel<<<1, 128, 0, stream>>>(Wgcn, bgcn, W1, b1, fold);
    deg_kernel<<<4096, 256, 0, stream>>>((const i32x4*)(ei + N_EDGES), deg);
    scan1_kernel<<<NSCANBLK, 256, 0, stream>>>(deg, blocksum);
    scan2_kernel<<<1, 256, 0, stream>>>(blocksum);
    scan3_kernel<<<NSCANBLK, 256, 0, stream>>>(deg, blocksum, cursor);
    dinv_dsi_kernel<<<(N_NODES + 255) / 256, 256, 0, stream>>>(
        deg, (const float4*)state, dsi4, use_dsi ? 1 : 0);
    place_kernel<<<8192, 256, 0, stream>>>(
        (const i32x4*)ei, (const i32x4*)(ei + N_EDGES), cursor, recs);
    if (use_dsi)
      reduce_kernel<true><<<(N_GRAPHS + 255) / 256, 256, 0, stream>>>(
          cursor, recs, (const float*)deg, dsi4, (const float4*)state,
          W1, fold, W2, b2, out);
    else
      reduce_kernel<false><<<(N_GRAPHS + 255) / 256, 256, 0, stream>>>(
          cursor, recs, (const float*)deg, dsi4, (const float4*)state,
          W1, fold, W2, b2, out);
  } else {
    // fallback: round-3 atomic-scatter path (needs 33 MB)
    unsigned* deg  = (unsigned*)ws;
    float*    acc  = (float*)(ws + 16 * MB);
    float*    fold = (float*)(ws + 32 * MB);
    (void)hipMemsetAsync(d_ws, 0, 32 * MB + 1024, stream);
    fold_kernel<<<1, 128, 0, stream>>>(Wgcn, bgcn, W1, b1, fold);
    deg_kernel<<<4096, 256, 0, stream>>>((const i32x4*)(ei + N_EDGES), deg);
    dinv_kernel<<<(N_NODES + 255) / 256, 256, 0, stream>>>(deg);
    scatter_kernel<<<8192, 256, 0, stream>>>(
        (const i32x4*)ei, (const i32x4*)(ei + N_EDGES),
        (const float*)deg, (const float4*)state, acc);
    final_kernel<<<(N_GRAPHS + 255) / 256, 256, 0, stream>>>(
        (const float4*)state, (const float4*)deg, (const float4*)acc,
        W1, fold, W2, b2, out);
  }
}

// Round 5
// 688.258 us; speedup vs baseline: 4.1831x; 2.6744x over previous
//
#include <hip/hip_runtime.h>

typedef unsigned long long u64;
typedef __attribute__((ext_vector_type(4))) int i32x4;
typedef __attribute__((ext_vector_type(4))) unsigned u32x4;

#define N_NODES   4000000
#define N_EDGES   12000000
#define N_GRAPHS  1000000

// ---- bin-path params ----
#define NBIN      489        // ceil(1e6 / 2048) bins by dst graph
#define GPBIN     2048       // graphs per bin (2^11)
#define NPBIN     8192       // nodes per bin
#define BINCAP    28672      // recs capacity per bin (mean 24576, +26 sigma)
#define LCAP      24         // LDS staging recs per bin
#define ABLOCKS   256
#define EPB       46875      // edges per block: ABLOCKS*EPB == N_EDGES

// ---- sort-path params (round-4 fallback) ----
#define GPB       1024
#define NSCANBLK  1024

// ================= shared small kernels =================

__global__ __launch_bounds__(256) void fold_kernel(
    const float* __restrict__ Wgcn, const float* __restrict__ bgcn,
    const float* __restrict__ W1, const float* __restrict__ b1,
    float* __restrict__ fold) {
  int t = threadIdx.x;
  if (t < 128) {
    int j = t >> 2, c = t & 3;
    float s = 0.f;
    for (int k = 0; k < 32; ++k) s += Wgcn[c * 32 + k] * W1[(4 + k) * 32 + j];
    fold[j * 4 + c] = s;                    // Wg1T[j][c]
  }
  if (t < 32) {
    float s = 0.f;
    for (int k = 0; k < 32; ++k) s += bgcn[k] * W1[(4 + k) * 32 + t];
    fold[128 + t] = b1[t] + 4.0f * s;       // b1p[j]
  }
}

// ================= bin path =================

__global__ __launch_bounds__(512) void binscatter_kernel(
    const int* __restrict__ src, const int* __restrict__ dst,
    unsigned* __restrict__ gcur, u64* __restrict__ recs) {
  extern __shared__ char smem[];
  u64* buf = (u64*)smem;                              // [512*LCAP]
  unsigned* cnt = (unsigned*)(smem + 512 * LCAP * 8); // [512]
  int t = threadIdx.x;
  if (t < 512) cnt[t] = 0;
  __syncthreads();
  const int base = blockIdx.x * EPB;
  const int nrounds = (EPB + 1023) / 1024;

  int cs0 = 0, cd0 = 0, cs1 = 0, cd1 = 0;
  {
    int off = t;
    if (off < EPB) { cs0 = __builtin_nontemporal_load(src + base + off);
                     cd0 = __builtin_nontemporal_load(dst + base + off); }
    off += 512;
    if (off < EPB) { cs1 = __builtin_nontemporal_load(src + base + off);
                     cd1 = __builtin_nontemporal_load(dst + base + off); }
  }
  for (int r = 0; r < nrounds; ++r) {
    // prefetch next round
    int ns0 = 0, nd0 = 0, ns1 = 0, nd1 = 0;
    if (r + 1 < nrounds) {
      int off = (r + 1) * 1024 + t;
      if (off < EPB) { ns0 = __builtin_nontemporal_load(src + base + off);
                       nd0 = __builtin_nontemporal_load(dst + base + off); }
      off += 512;
      if (off < EPB) { ns1 = __builtin_nontemporal_load(src + base + off);
                       nd1 = __builtin_nontemporal_load(dst + base + off); }
    }
    // append current round
    int off = r * 1024 + t;
#pragma unroll
    for (int k = 0; k < 2; ++k) {
      int o = off + k * 512;
      if (o < EPB) {
        int s = k ? cs1 : cs0;
        int d = k ? cd1 : cd0;
        unsigned graph = (unsigned)d >> 2;
        unsigned bin   = graph >> 11;
        unsigned glo   = graph & 2047u;
        u64 rec = ((u64)glo << 32) | ((u64)((unsigned)s << 2) | (unsigned)(d & 3));
        unsigned idx = atomicAdd(&cnt[bin], 1u);
        if (idx < LCAP) buf[bin * LCAP + idx] = rec;
        else {  // rare spill: direct global append
          unsigned p = atomicAdd(&gcur[bin], 1u);
          if (p < BINCAP) recs[(size_t)bin * BINCAP + p] = rec;
        }
      }
    }
    __syncthreads();
    // flush phase: one bin per thread
    bool fin = (r == nrounds - 1);
    if (t < 512) {
      int bin = t;
      unsigned c = cnt[bin]; if (c > LCAP) c = LCAP;
      unsigned n = fin ? c : (c & ~15u);
      if (n) {
        unsigned pos = atomicAdd(&gcur[bin], n);
        if (pos + n <= BINCAP) {
          u64* dp = recs + (size_t)bin * BINCAP + pos;
          for (unsigned i = 0; i < n; ++i) dp[i] = buf[bin * LCAP + i];
        }
      }
      unsigned rem = c - n;
      for (unsigned i = 0; i < rem; ++i) buf[bin * LCAP + i] = buf[bin * LCAP + n + i];
      cnt[bin] = rem;
    }
    __syncthreads();
    cs0 = ns0; cd0 = nd0; cs1 = ns1; cd1 = nd1;
  }
}

__global__ __launch_bounds__(256) void bindeg_kernel(
    const u64* __restrict__ recs, const unsigned* __restrict__ gcur,
    float* __restrict__ dinv) {
  __shared__ unsigned degL[NPBIN];
  int t = threadIdx.x, bin = blockIdx.x;
  for (int i = t; i < NPBIN; i += 256) degL[i] = 0;
  __syncthreads();
  unsigned n = gcur[bin]; if (n > BINCAP) n = BINCAP;
  const u64* rp = recs + (size_t)bin * BINCAP;
  for (unsigned i = t; i < n; i += 256) {
    u64 v = rp[i];
    unsigned lo = (unsigned)v, glo = (unsigned)(v >> 32);
    atomicAdd(&degL[glo * 4 + (lo & 3u)], 1u);
  }
  __syncthreads();
  int nb = bin * NPBIN;
  for (int i = t; i < NPBIN; i += 256) {
    int node = nb + i;
    if (node < N_NODES) dinv[node] = rsqrtf((float)(degL[i] + 1u));
  }
}

__global__ __launch_bounds__(256) void binreduce_kernel(
    const u64* __restrict__ recs, const unsigned* __restrict__ gcur,
    const float* __restrict__ dinv, const float4* __restrict__ state4,
    const float* __restrict__ W1, const float* __restrict__ fold,
    const float* __restrict__ W2, const float* __restrict__ b2,
    float* __restrict__ out) {
  extern __shared__ float dynsm[];
  float* dinvL = dynsm;           // [NPBIN]
  float* accL  = dynsm + NPBIN;   // [NPBIN] = [GPBIN][4]
  __shared__ float4 w1aT[32], wg1T[32];
  __shared__ float b1p[32], w2s[32];
  int t = threadIdx.x, bin = blockIdx.x;
  if (t < 32) {
    w1aT[t] = make_float4(W1[t], W1[32 + t], W1[64 + t], W1[96 + t]);
    wg1T[t] = ((const float4*)fold)[t];
    b1p[t]  = fold[128 + t];
    w2s[t]  = W2[t];
  }
  int nb = bin * NPBIN;
  for (int i = t; i < NPBIN; i += 256) {
    int node = nb + i;
    dinvL[i] = (node < N_NODES) ? dinv[node] : 0.f;
    accL[i]  = 0.f;
  }
  __syncthreads();
  unsigned n = gcur[bin]; if (n > BINCAP) n = BINCAP;
  const u64* rp = recs + (size_t)bin * BINCAP;
  for (unsigned i = t; i < n; i += 256) {
    u64 v = rp[i];
    unsigned lo = (unsigned)v, glo = (unsigned)(v >> 32);
    unsigned s = lo >> 2, rr = lo & 3u;
    float w = dinvL[glo * 4 + rr] * dinv[s];
    float4 st = state4[s];
    float* a = accL + glo * 4;
    atomicAdd(a + 0, w * st.x);
    atomicAdd(a + 1, w * st.y);
    atomicAdd(a + 2, w * st.z);
    atomicAdd(a + 3, w * st.w);
  }
  __syncthreads();
  for (int gi = t; gi < GPBIN; gi += 256) {
    int g = bin * GPBIN + gi;
    if (g >= N_GRAPHS) break;
    float4 s0 = state4[4 * g + 0], s1 = state4[4 * g + 1];
    float4 s2 = state4[4 * g + 2], s3 = state4[4 * g + 3];
    float d0 = dinvL[gi * 4 + 0], d1 = dinvL[gi * 4 + 1];
    float d2 = dinvL[gi * 4 + 2], d3 = dinvL[gi * 4 + 3];
    float q0 = d0 * d0, q1 = d1 * d1, q2 = d2 * d2, q3 = d3 * d3;
    float ax = accL[gi * 4 + 0] + q0 * s0.x + q1 * s1.x + q2 * s2.x + q3 * s3.x;
    float ay = accL[gi * 4 + 1] + q0 * s0.y + q1 * s1.y + q2 * s2.y + q3 * s3.y;
    float az = accL[gi * 4 + 2] + q0 * s0.z + q1 * s1.z + q2 * s2.z + q3 * s3.z;
    float aw = accL[gi * 4 + 3] + q0 * s0.w + q1 * s1.w + q2 * s2.w + q3 * s3.w;
    float vx = s0.x + s1.x + s2.x + s3.x;
    float vy = s0.y + s1.y + s2.y + s3.y;
    float vz = s0.z + s1.z + s2.z + s3.z;
    float vw = s0.w + s1.w + s2.w + s3.w;
    float accum = b2[0];
#pragma unroll
    for (int j = 0; j < 32; ++j) {
      float4 wa = w1aT[j], wg = wg1T[j];
      float h = b1p[j]
              + vx * wa.x + vy * wa.y + vz * wa.z + vw * wa.w
              + ax * wg.x + ay * wg.y + az * wg.z + aw * wg.w;
      accum += fmaxf(h, 0.f) * w2s[j];
    }
    out[g] = accum;
  }
}

// ================= sort path (round-4 fallback) =================

__global__ __launch_bounds__(256) void deg_kernel(
    const i32x4* __restrict__ dst4, unsigned* __restrict__ deg) {
  int stride = gridDim.x * blockDim.x;
  for (int e = blockIdx.x * blockDim.x + threadIdx.x; e < N_EDGES / 4; e += stride) {
    i32x4 d = __builtin_nontemporal_load(dst4 + e);
    atomicAdd(&deg[d.x], 1u);
    atomicAdd(&deg[d.y], 1u);
    atomicAdd(&deg[d.z], 1u);
    atomicAdd(&deg[d.w], 1u);
  }
}

__global__ __launch_bounds__(256) void scan1_kernel(
    const unsigned* __restrict__ deg, unsigned* __restrict__ blocksum) {
  int t = threadIdx.x;
  int gb = blockIdx.x * GPB + t * 4;
  unsigned s = 0;
#pragma unroll
  for (int i = 0; i < 4; ++i) {
    int g = gb + i;
    if (g < N_GRAPHS) {
      u32x4 v = ((const u32x4*)deg)[g];
      s += v.x + v.y + v.z + v.w;
    }
  }
  __shared__ unsigned red[256];
  red[t] = s; __syncthreads();
  for (int off = 128; off > 0; off >>= 1) {
    if (t < off) red[t] += red[t + off];
    __syncthreads();
  }
  if (t == 0) blocksum[blockIdx.x] = red[0];
}

__global__ __launch_bounds__(256) void scan2_kernel(unsigned* __restrict__ blocksum) {
  int t = threadIdx.x;
  u32x4 v = ((const u32x4*)blocksum)[t];
  unsigned s1 = v.x + v.y, s2 = s1 + v.z, s3 = s2 + v.w;
  __shared__ unsigned tsum[256];
  tsum[t] = s3; __syncthreads();
  for (int off = 1; off < 256; off <<= 1) {
    unsigned add = (t >= off) ? tsum[t - off] : 0u;
    __syncthreads();
    tsum[t] += add;
    __syncthreads();
  }
  unsigned base = t ? tsum[t - 1] : 0u;
  u32x4 o; o.x = base; o.y = base + v.x; o.z = base + s1; o.w = base + s2;
  ((u32x4*)blocksum)[t] = o;
}

__global__ __launch_bounds__(256) void scan3_kernel(
    const unsigned* __restrict__ deg, const unsigned* __restrict__ blocksum,
    unsigned* __restrict__ cursor) {
  int t = threadIdx.x;
  int gb = blockIdx.x * GPB + t * 4;
  unsigned c[4];
#pragma unroll
  for (int i = 0; i < 4; ++i) {
    int g = gb + i;
    if (g < N_GRAPHS) {
      u32x4 v = ((const u32x4*)deg)[g];
      c[i] = v.x + v.y + v.z + v.w;
    } else c[i] = 0;
  }
  unsigned s3 = c[0] + c[1] + c[2] + c[3];
  __shared__ unsigned tsum[256];
  tsum[t] = s3; __syncthreads();
  for (int off = 1; off < 256; off <<= 1) {
    unsigned add = (t >= off) ? tsum[t - off] : 0u;
    __syncthreads();
    tsum[t] += add;
    __syncthreads();
  }
  unsigned base = blocksum[blockIdx.x] + (t ? tsum[t - 1] : 0u);
  if (gb < N_GRAPHS) {
    u32x4 o; o.x = base; o.y = base + c[0]; o.z = base + c[0] + c[1];
    o.w = base + c[0] + c[1] + c[2];
    ((u32x4*)cursor)[gb >> 2] = o;
  }
}

__global__ __launch_bounds__(256) void dinv_dsi_kernel(
    unsigned* __restrict__ degdinv, const float4* __restrict__ state4,
    float4* __restrict__ dsi4, int use_dsi) {
  int i = blockIdx.x * blockDim.x + threadIdx.x;
  if (i < N_NODES) {
    float dv = rsqrtf((float)(degdinv[i] + 1u));
    reinterpret_cast<float*>(degdinv)[i] = dv;
    if (use_dsi) {
      float4 s = state4[i];
      dsi4[i] = make_float4(dv * s.x, dv * s.y, dv * s.z, dv * s.w);
    }
  }
}

__global__ __launch_bounds__(256) void place_kernel(
    const i32x4* __restrict__ src4, const i32x4* __restrict__ dst4,
    unsigned* __restrict__ cursor, unsigned* __restrict__ recs) {
  int stride = gridDim.x * blockDim.x;
  for (int e = blockIdx.x * blockDim.x + threadIdx.x; e < N_EDGES / 4; e += stride) {
    i32x4 s4 = __builtin_nontemporal_load(src4 + e);
    i32x4 d4 = __builtin_nontemporal_load(dst4 + e);
#pragma unroll
    for (int u = 0; u < 4; ++u) {
      int s = (u == 0) ? s4.x : (u == 1) ? s4.y : (u == 2) ? s4.z : s4.w;
      int d = (u == 0) ? d4.x : (u == 1) ? d4.y : (u == 2) ? d4.z : d4.w;
      unsigned p = atomicAdd(&cursor[d >> 2], 1u);
      __builtin_nontemporal_store(((unsigned)s << 2) | (unsigned)(d & 3), &recs[p]);
    }
  }
}

template <bool DSI>
__global__ __launch_bounds__(256) void reduce_kernel(
    const unsigned* __restrict__ cursor, const unsigned* __restrict__ recs,
    const float* __restrict__ dinv, const float4* __restrict__ dsi4,
    const float4* __restrict__ state4,
    const float* __restrict__ W1, const float* __restrict__ fold,
    const float* __restrict__ W2, const float* __restrict__ b2,
    float* __restrict__ out) {
  __shared__ float4 w1aT[32];
  __shared__ float4 wg1T[32];
  __shared__ float b1p[32];
  __shared__ float w2s[32];
  int t = threadIdx.x;
  if (t < 32) {
    w1aT[t] = make_float4(W1[t], W1[32 + t], W1[64 + t], W1[96 + t]);
    wg1T[t] = ((const float4*)fold)[t];
    b1p[t]  = fold[128 + t];
    w2s[t]  = W2[t];
  }
  __syncthreads();
  int g = blockIdx.x * blockDim.x + t;
  if (g >= N_GRAPHS) return;
  unsigned start = g ? cursor[g - 1] : 0u;
  unsigned end   = cursor[g];
  float4 dv = ((const float4*)dinv)[g];
  float4 a = make_float4(0.f, 0.f, 0.f, 0.f);
  for (unsigned p = start; p < end; ++p) {
    unsigned rec = recs[p];
    unsigned s = rec >> 2;
    unsigned r = rec & 3u;
    float wd = (r == 0) ? dv.x : (r == 1) ? dv.y : (r == 2) ? dv.z : dv.w;
    if (DSI) {
      float4 m = dsi4[s];
      a.x += wd * m.x; a.y += wd * m.y; a.z += wd * m.z; a.w += wd * m.w;
    } else {
      float w = wd * dinv[s];
      float4 st = state4[s];
      a.x += w * st.x; a.y += w * st.y; a.z += w * st.z; a.w += w * st.w;
    }
  }
  float4 s0 = state4[4 * g + 0], s1 = state4[4 * g + 1];
  float4 s2 = state4[4 * g + 2], s3 = state4[4 * g + 3];
  float q0 = dv.x * dv.x, q1 = dv.y * dv.y, q2 = dv.z * dv.z, q3 = dv.w * dv.w;
  a.x += q0 * s0.x + q1 * s1.x + q2 * s2.x + q3 * s3.x;
  a.y += q0 * s0.y + q1 * s1.y + q2 * s2.y + q3 * s3.y;
  a.z += q0 * s0.z + q1 * s1.z + q2 * s2.z + q3 * s3.z;
  a.w += q0 * s0.w + q1 * s1.w + q2 * s2.w + q3 * s3.w;
  float4 vs;
  vs.x = s0.x + s1.x + s2.x + s3.x;
  vs.y = s0.y + s1.y + s2.y + s3.y;
  vs.z = s0.z + s1.z + s2.z + s3.z;
  vs.w = s0.w + s1.w + s2.w + s3.w;
  float accum = b2[0];
#pragma unroll
  for (int j = 0; j < 32; ++j) {
    float4 wa = w1aT[j], wg = wg1T[j];
    float h = b1p[j]
            + vs.x * wa.x + vs.y * wa.y + vs.z * wa.z + vs.w * wa.w
            + a.x * wg.x + a.y * wg.y + a.z * wg.z + a.w * wg.w;
    accum += fmaxf(h, 0.f) * w2s[j];
  }
  out[g] = accum;
}

// ================= atomic-scatter path (round-3 fallback) =================

__global__ __launch_bounds__(256) void dinv_kernel(unsigned* __restrict__ degdinv) {
  int i = blockIdx.x * blockDim.x + threadIdx.x;
  if (i < N_NODES) {
    float dv = rsqrtf((float)(degdinv[i] + 1u));
    reinterpret_cast<float*>(degdinv)[i] = dv;
  }
}

__global__ __launch_bounds__(256) void scatter_kernel(
    const i32x4* __restrict__ src4, const i32x4* __restrict__ dst4,
    const float* __restrict__ dinv, const float4* __restrict__ state4,
    float* __restrict__ acc) {
  int stride = gridDim.x * blockDim.x;
  for (int e = blockIdx.x * blockDim.x + threadIdx.x; e < N_EDGES / 4; e += stride) {
    i32x4 s4 = __builtin_nontemporal_load(src4 + e);
    i32x4 d4 = __builtin_nontemporal_load(dst4 + e);
#pragma unroll
    for (int u = 0; u < 4; ++u) {
      int s = (u == 0) ? s4.x : (u == 1) ? s4.y : (u == 2) ? s4.z : s4.w;
      int d = (u == 0) ? d4.x : (u == 1) ? d4.y : (u == 2) ? d4.z : d4.w;
      float w = dinv[s] * dinv[d];
      float4 st = state4[s];
      float* base = acc + (size_t)(d >> 2) * 4;
      atomicAdd(base + 0, w * st.x);
      atomicAdd(base + 1, w * st.y);
      atomicAdd(base + 2, w * st.z);
      atomicAdd(base + 3, w * st.w);
    }
  }
}

__global__ __launch_bounds__(256) void final_kernel(
    const float4* __restrict__ state4, const float4* __restrict__ dinv4,
    const float4* __restrict__ acc4, const float* __restrict__ W1,
    const float* __restrict__ fold, const float* __restrict__ W2,
    const float* __restrict__ b2, float* __restrict__ out) {
  __shared__ float4 w1aT[32];
  __shared__ float4 wg1T[32];
  __shared__ float b1p[32];
  __shared__ float w2s[32];
  int t = threadIdx.x;
  if (t < 32) {
    w1aT[t] = make_float4(W1[t], W1[32 + t], W1[64 + t], W1[96 + t]);
    wg1T[t] = ((const float4*)fold)[t];
    b1p[t]  = fold[128 + t];
    w2s[t]  = W2[t];
  }
  __syncthreads();
  int b = blockIdx.x * blockDim.x + t;
  if (b >= N_GRAPHS) return;
  float4 s0 = state4[4 * b + 0], s1 = state4[4 * b + 1];
  float4 s2 = state4[4 * b + 2], s3 = state4[4 * b + 3];
  float4 dv = dinv4[b];
  float4 a  = acc4[b];
  float q0 = dv.x * dv.x, q1 = dv.y * dv.y, q2 = dv.z * dv.z, q3 = dv.w * dv.w;
  a.x += q0 * s0.x + q1 * s1.x + q2 * s2.x + q3 * s3.x;
  a.y += q0 * s0.y + q1 * s1.y + q2 * s2.y + q3 * s3.y;
  a.z += q0 * s0.z + q1 * s1.z + q2 * s2.z + q3 * s3.z;
  a.w += q0 * s0.w + q1 * s1.w + q2 * s2.w + q3 * s3.w;
  float4 vs;
  vs.x = s0.x + s1.x + s2.x + s3.x;
  vs.y = s0.y + s1.y + s2.y + s3.y;
  vs.z = s0.z + s1.z + s2.z + s3.z;
  vs.w = s0.w + s1.w + s2.w + s3.w;
  float accum = b2[0];
#pragma unroll
  for (int j = 0; j < 32; ++j) {
    float4 wa = w1aT[j], wg = wg1T[j];
    float h = b1p[j]
            + vs.x * wa.x + vs.y * wa.y + vs.z * wa.z + vs.w * wa.w
            + a.x * wg.x + a.y * wg.y + a.z * wg.z + a.w * wg.w;
    accum += fmaxf(h, 0.f) * w2s[j];
  }
  out[b] = accum;
}

// ================= launch =================

extern "C" void kernel_launch(void* const* d_in, const int* in_sizes, int n_in,
                              void* d_out, int out_size, void* d_ws, size_t ws_size,
                              hipStream_t stream) {
  const float* state = (const float*)d_in[0];
  const int*   ei    = (const int*)d_in[1];   // int32: [2][N_EDGES]
  const float* Wgcn  = (const float*)d_in[2];
  const float* bgcn  = (const float*)d_in[3];
  const float* W1    = (const float*)d_in[4];
  const float* b1    = (const float*)d_in[5];
  const float* W2    = (const float*)d_in[6];
  const float* b2    = (const float*)d_in[7];
  float* out = (float*)d_out;

  char* ws = (char*)d_ws;
  const size_t MB = 1024u * 1024u;

  // bin-path layout
  const size_t recs_bytes = (size_t)NBIN * BINCAP * 8;          // 112,197,632
  const size_t dinv_off   = recs_bytes;                          // 16 MB dinv
  const size_t gcur_off   = dinv_off + (size_t)N_NODES * 4;      // aligned (256)
  const size_t fold_off   = gcur_off + 4096;
  const size_t need_bin   = fold_off + 1024;                     // ~128.2 MB

  if (ws_size >= need_bin) {
    u64*      recs = (u64*)ws;
    float*    dinv = (float*)(ws + dinv_off);
    unsigned* gcur = (unsigned*)(ws + gcur_off);
    float*    fold = (float*)(ws + fold_off);

    (void)hipMemsetAsync(gcur, 0, 4096, stream);
    fold_kernel<<<1, 128, 0, stream>>>(Wgcn, bgcn, W1, b1, fold);
    binscatter_kernel<<<ABLOCKS, 512, 512 * LCAP * 8 + 512 * 4, stream>>>(
        ei, ei + N_EDGES, gcur, recs);
    bindeg_kernel<<<NBIN, 256, 0, stream>>>(recs, gcur, dinv);
    binreduce_kernel<<<NBIN, 256, 2 * NPBIN * 4, stream>>>(
        recs, gcur, dinv, (const float4*)state, W1, fold, W2, b2, out);
    return;
  }

  const size_t need_dsi   = 137 * MB;
  const size_t need_nodsi = 74 * MB;

  if (ws_size >= need_nodsi) {
    bool use_dsi = (ws_size >= need_dsi);
    unsigned* deg      = (unsigned*)ws;
    unsigned* cursor   = (unsigned*)(ws + 16 * MB);
    unsigned* blocksum = (unsigned*)(ws + 20 * MB);
    float*    fold     = (float*)(ws + 20 * MB + 8192);
    float4*   dsi4     = (float4*)(ws + 24 * MB);
    unsigned* srecs    = (unsigned*)(ws + (use_dsi ? 88 * MB : 24 * MB));

    (void)hipMemsetAsync(deg, 0, 16 * MB, stream);
    fold_kernel<<<1, 128, 0, stream>>>(Wgcn, bgcn, W1, b1, fold);
    deg_kernel<<<4096, 256, 0, stream>>>((const i32x4*)(ei + N_EDGES), deg);
    scan1_kernel<<<NSCANBLK, 256, 0, stream>>>(deg, blocksum);
    scan2_kernel<<<1, 256, 0, stream>>>(blocksum);
    scan3_kernel<<<NSCANBLK, 256, 0, stream>>>(deg, blocksum, cursor);
    dinv_dsi_kernel<<<(N_NODES + 255) / 256, 256, 0, stream>>>(
        deg, (const float4*)state, dsi4, use_dsi ? 1 : 0);
    place_kernel<<<8192, 256, 0, stream>>>(
        (const i32x4*)ei, (const i32x4*)(ei + N_EDGES), cursor, srecs);
    if (use_dsi)
      reduce_kernel<true><<<(N_GRAPHS + 255) / 256, 256, 0, stream>>>(
          cursor, srecs, (const float*)deg, dsi4, (const float4*)state,
          W1, fold, W2, b2, out);
    else
      reduce_kernel<false><<<(N_GRAPHS + 255) / 256, 256, 0, stream>>>(
          cursor, srecs, (const float*)deg, dsi4, (const float4*)state,
          W1, fold, W2, b2, out);
  } else {
    unsigned* deg  = (unsigned*)ws;
    float*    acc  = (float*)(ws + 16 * MB);
    float*    fold = (float*)(ws + 32 * MB);
    (void)hipMemsetAsync(d_ws, 0, 32 * MB + 1024, stream);
    fold_kernel<<<1, 128, 0, stream>>>(Wgcn, bgcn, W1, b1, fold);
    deg_kernel<<<4096, 256, 0, stream>>>((const i32x4*)(ei + N_EDGES), deg);
    dinv_kernel<<<(N_NODES + 255) / 256, 256, 0, stream>>>(deg);
    scatter_kernel<<<8192, 256, 0, stream>>>(
        (const i32x4*)ei, (const i32x4*)(ei + N_EDGES),
        (const float*)deg, (const float4*)state, acc);
    final_kernel<<<(N_GRAPHS + 255) / 256, 256, 0, stream>>>(
        (const float4*)state, (const float4*)deg, (const float4*)acc,
        W1, fold, W2, b2, out);
  }
}

// Round 6
// 567.155 us; speedup vs baseline: 5.0763x; 1.2135x over previous
//
#include <hip/hip_runtime.h>

typedef unsigned long long u64;
typedef __attribute__((ext_vector_type(4))) int i32x4;

#define N_NODES   4000000
#define N_EDGES   12000000
#define N_GRAPHS  1000000

// ---- bin-path params ----
#define NBIN      489        // bins of 2048 dst-graphs
#define GPBIN     2048
#define NPBIN     8192       // nodes per bin
#define BINCAP    28672      // recs/bin capacity (mean 24576, +26 sigma)
#define LCAP      16         // LDS staging recs per bin
#define SBLOCKS   512
#define SEPB      23438      // ceil(12M/512)

// ================= shared =================

__global__ __launch_bounds__(256) void fold_kernel(
    const float* __restrict__ Wgcn, const float* __restrict__ bgcn,
    const float* __restrict__ W1, const float* __restrict__ b1,
    float* __restrict__ fold) {
  int t = threadIdx.x;
  if (t < 128) {
    int j = t >> 2, c = t & 3;
    float s = 0.f;
    for (int k = 0; k < 32; ++k) s += Wgcn[c * 32 + k] * W1[(4 + k) * 32 + j];
    fold[j * 4 + c] = s;                    // Wg1T[j][c]
  }
  if (t < 32) {
    float s = 0.f;
    for (int k = 0; k < 32; ++k) s += bgcn[k] * W1[(4 + k) * 32 + t];
    fold[128 + t] = b1[t] + 4.0f * s;       // b1p[j]
  }
}

// ================= bin path =================

__global__ __launch_bounds__(512) void binscatter_kernel(
    const int* __restrict__ src, const int* __restrict__ dst,
    unsigned* __restrict__ gcur, u64* __restrict__ recs) {
  extern __shared__ char smem[];
  u64* buf = (u64*)smem;                               // [NBIN*LCAP]
  unsigned* cnt = (unsigned*)(smem + NBIN * LCAP * 8); // [NBIN]
  int t = threadIdx.x;
  for (int i = t; i < NBIN; i += 512) cnt[i] = 0;
  __syncthreads();
  const int base = blockIdx.x * SEPB;
  const int limit = min(SEPB, N_EDGES - base);
  const int nrounds = (limit + 1023) / 1024;

  int cs0 = 0, cd0 = 0, cs1 = 0, cd1 = 0;
  {
    int off = t;
    if (off < limit) { cs0 = __builtin_nontemporal_load(src + base + off);
                       cd0 = __builtin_nontemporal_load(dst + base + off); }
    off += 512;
    if (off < limit) { cs1 = __builtin_nontemporal_load(src + base + off);
                       cd1 = __builtin_nontemporal_load(dst + base + off); }
  }
  for (int r = 0; r < nrounds; ++r) {
    int ns0 = 0, nd0 = 0, ns1 = 0, nd1 = 0;
    if (r + 1 < nrounds) {
      int off = (r + 1) * 1024 + t;
      if (off < limit) { ns0 = __builtin_nontemporal_load(src + base + off);
                         nd0 = __builtin_nontemporal_load(dst + base + off); }
      off += 512;
      if (off < limit) { ns1 = __builtin_nontemporal_load(src + base + off);
                         nd1 = __builtin_nontemporal_load(dst + base + off); }
    }
    int off = r * 1024 + t;
#pragma unroll
    for (int k = 0; k < 2; ++k) {
      int o = off + k * 512;
      if (o < limit) {
        int s = k ? cs1 : cs0;
        int d = k ? cd1 : cd0;
        unsigned graph = (unsigned)d >> 2;
        unsigned bin   = graph >> 11;
        unsigned glo   = graph & 2047u;
        u64 rec = ((u64)glo << 32) | ((u64)((unsigned)s << 2) | (unsigned)(d & 3));
        unsigned idx = atomicAdd(&cnt[bin], 1u);
        if (idx < LCAP) buf[bin * LCAP + idx] = rec;
        else {  // rare spill
          unsigned p = atomicAdd(&gcur[bin], 1u);
          if (p < BINCAP) recs[(size_t)bin * BINCAP + p] = rec;
        }
      }
    }
    __syncthreads();
    bool fin = (r == nrounds - 1);
    if (t < NBIN) {
      int bin = t;
      unsigned c = cnt[bin]; if (c > LCAP) c = LCAP;
      unsigned n = fin ? c : (c & ~7u);   // multiples of 8 recs = 64B bursts
      if (n) {
        unsigned pos = atomicAdd(&gcur[bin], n);
        if (pos + n <= BINCAP) {
          u64* dp = recs + (size_t)bin * BINCAP + pos;
          for (unsigned i = 0; i < n; ++i) dp[i] = buf[bin * LCAP + i];
        }
      }
      unsigned rem = c - n;
      for (unsigned i = 0; i < rem; ++i) buf[bin * LCAP + i] = buf[bin * LCAP + n + i];
      cnt[bin] = rem;
    }
    __syncthreads();
    cs0 = ns0; cd0 = nd0; cs1 = ns1; cd1 = nd1;
  }
}

template <bool DSI>
__global__ __launch_bounds__(512) void bindeg_kernel(
    const u64* __restrict__ recs, const unsigned* __restrict__ gcur,
    const float4* __restrict__ state4,
    float* __restrict__ dinv, float4* __restrict__ dsi4) {
  __shared__ unsigned degL[NPBIN];
  int t = threadIdx.x, bin = blockIdx.x;
  for (int i = t; i < NPBIN; i += 512) degL[i] = 0;
  __syncthreads();
  unsigned n = gcur[bin]; if (n > BINCAP) n = BINCAP;
  const u64* rp = recs + (size_t)bin * BINCAP;
  for (unsigned i = t; i < n; i += 512) {
    u64 v = __builtin_nontemporal_load(rp + i);
    unsigned lo = (unsigned)v, glo = (unsigned)(v >> 32);
    atomicAdd(&degL[glo * 4 + (lo & 3u)], 1u);
  }
  __syncthreads();
  int nb = bin * NPBIN;
  for (int i = t; i < NPBIN; i += 512) {
    int node = nb + i;
    if (node < N_NODES) {
      float dv = rsqrtf((float)(degL[i] + 1u));
      dinv[node] = dv;
      if (DSI) {
        float4 s = state4[node];
        dsi4[node] = make_float4(dv * s.x, dv * s.y, dv * s.z, dv * s.w);
      }
    }
  }
}

template <bool DSI>
__global__ __launch_bounds__(512, 4) void binreduce_kernel(
    const u64* __restrict__ recs, const unsigned* __restrict__ gcur,
    const float* __restrict__ dinv, const float4* __restrict__ dsi4,
    const float4* __restrict__ state4,
    const float* __restrict__ W1, const float* __restrict__ fold,
    const float* __restrict__ W2, const float* __restrict__ b2,
    float* __restrict__ out) {
  extern __shared__ float dynsm[];
  float* dinvL = dynsm;           // [NPBIN]
  float* accL  = dynsm + NPBIN;   // [NPBIN]
  __shared__ float4 w1aT[32], wg1T[32];
  __shared__ float b1p[32], w2s[32];
  int t = threadIdx.x, bin = blockIdx.x;
  if (t < 32) {
    w1aT[t] = make_float4(W1[t], W1[32 + t], W1[64 + t], W1[96 + t]);
    wg1T[t] = ((const float4*)fold)[t];
    b1p[t]  = fold[128 + t];
    w2s[t]  = W2[t];
  }
  int nb = bin * NPBIN;
  for (int i = t; i < NPBIN; i += 512) {
    int node = nb + i;
    dinvL[i] = (node < N_NODES) ? dinv[node] : 0.f;
    accL[i]  = 0.f;
  }
  __syncthreads();
  unsigned n = gcur[bin]; if (n > BINCAP) n = BINCAP;
  const u64* rp = recs + (size_t)bin * BINCAP;
  unsigned q = n >> 2;
  for (unsigned i = t; i < q; i += 512) {
    u64 v0 = __builtin_nontemporal_load(rp + i);
    u64 v1 = __builtin_nontemporal_load(rp + i + q);
    u64 v2 = __builtin_nontemporal_load(rp + i + 2 * q);
    u64 v3 = __builtin_nontemporal_load(rp + i + 3 * q);
    unsigned lo0 = (unsigned)v0, g0 = (unsigned)(v0 >> 32);
    unsigned lo1 = (unsigned)v1, g1 = (unsigned)(v1 >> 32);
    unsigned lo2 = (unsigned)v2, g2 = (unsigned)(v2 >> 32);
    unsigned lo3 = (unsigned)v3, g3 = (unsigned)(v3 >> 32);
    unsigned s0 = lo0 >> 2, s1 = lo1 >> 2, s2 = lo2 >> 2, s3 = lo3 >> 2;
    float4 m0, m1, m2, m3;
    float w0 = dinvL[g0 * 4 + (lo0 & 3u)];
    float w1 = dinvL[g1 * 4 + (lo1 & 3u)];
    float w2 = dinvL[g2 * 4 + (lo2 & 3u)];
    float w3 = dinvL[g3 * 4 + (lo3 & 3u)];
    if (DSI) {
      m0 = dsi4[s0]; m1 = dsi4[s1]; m2 = dsi4[s2]; m3 = dsi4[s3];
    } else {
      m0 = state4[s0]; m1 = state4[s1]; m2 = state4[s2]; m3 = state4[s3];
      w0 *= dinv[s0]; w1 *= dinv[s1]; w2 *= dinv[s2]; w3 *= dinv[s3];
    }
    float* a0 = accL + g0 * 4;
    atomicAdd(a0 + 0, w0 * m0.x); atomicAdd(a0 + 1, w0 * m0.y);
    atomicAdd(a0 + 2, w0 * m0.z); atomicAdd(a0 + 3, w0 * m0.w);
    float* a1 = accL + g1 * 4;
    atomicAdd(a1 + 0, w1 * m1.x); atomicAdd(a1 + 1, w1 * m1.y);
    atomicAdd(a1 + 2, w1 * m1.z); atomicAdd(a1 + 3, w1 * m1.w);
    float* a2 = accL + g2 * 4;
    atomicAdd(a2 + 0, w2 * m2.x); atomicAdd(a2 + 1, w2 * m2.y);
    atomicAdd(a2 + 2, w2 * m2.z); atomicAdd(a2 + 3, w2 * m2.w);
    float* a3 = accL + g3 * 4;
    atomicAdd(a3 + 0, w3 * m3.x); atomicAdd(a3 + 1, w3 * m3.y);
    atomicAdd(a3 + 2, w3 * m3.z); atomicAdd(a3 + 3, w3 * m3.w);
  }
  unsigned rem = n & 3u;
  if ((unsigned)t < rem) {
    u64 v = rp[4 * q + t];
    unsigned lo = (unsigned)v, g = (unsigned)(v >> 32);
    unsigned s = lo >> 2;
    float w = dinvL[g * 4 + (lo & 3u)];
    float4 m;
    if (DSI) { m = dsi4[s]; }
    else { m = state4[s]; w *= dinv[s]; }
    float* a = accL + g * 4;
    atomicAdd(a + 0, w * m.x); atomicAdd(a + 1, w * m.y);
    atomicAdd(a + 2, w * m.z); atomicAdd(a + 3, w * m.w);
  }
  __syncthreads();
  for (int gi = t; gi < GPBIN; gi += 512) {
    int g = bin * GPBIN + gi;
    if (g >= N_GRAPHS) break;
    float4 s0 = state4[4 * g + 0], s1 = state4[4 * g + 1];
    float4 s2 = state4[4 * g + 2], s3 = state4[4 * g + 3];
    float d0 = dinvL[gi * 4 + 0], d1 = dinvL[gi * 4 + 1];
    float d2 = dinvL[gi * 4 + 2], d3 = dinvL[gi * 4 + 3];
    float q0 = d0 * d0, q1 = d1 * d1, q2 = d2 * d2, q3 = d3 * d3;
    float ax = accL[gi * 4 + 0] + q0 * s0.x + q1 * s1.x + q2 * s2.x + q3 * s3.x;
    float ay = accL[gi * 4 + 1] + q0 * s0.y + q1 * s1.y + q2 * s2.y + q3 * s3.y;
    float az = accL[gi * 4 + 2] + q0 * s0.z + q1 * s1.z + q2 * s2.z + q3 * s3.z;
    float aw = accL[gi * 4 + 3] + q0 * s0.w + q1 * s1.w + q2 * s2.w + q3 * s3.w;
    float vx = s0.x + s1.x + s2.x + s3.x;
    float vy = s0.y + s1.y + s2.y + s3.y;
    float vz = s0.z + s1.z + s2.z + s3.z;
    float vw = s0.w + s1.w + s2.w + s3.w;
    float accum = b2[0];
#pragma unroll 4
    for (int j = 0; j < 32; ++j) {
      float4 wa = w1aT[j], wg = wg1T[j];
      float h = b1p[j]
              + vx * wa.x + vy * wa.y + vz * wa.z + vw * wa.w
              + ax * wg.x + ay * wg.y + az * wg.z + aw * wg.w;
      accum += fmaxf(h, 0.f) * w2s[j];
    }
    out[g] = accum;
  }
}

// ================= round-3 fallback =================

__global__ __launch_bounds__(256) void deg_kernel(
    const i32x4* __restrict__ dst4, unsigned* __restrict__ deg) {
  int stride = gridDim.x * blockDim.x;
  for (int e = blockIdx.x * blockDim.x + threadIdx.x; e < N_EDGES / 4; e += stride) {
    i32x4 d = __builtin_nontemporal_load(dst4 + e);
    atomicAdd(&deg[d.x], 1u);
    atomicAdd(&deg[d.y], 1u);
    atomicAdd(&deg[d.z], 1u);
    atomicAdd(&deg[d.w], 1u);
  }
}

__global__ __launch_bounds__(256) void dinv_kernel(unsigned* __restrict__ degdinv) {
  int i = blockIdx.x * blockDim.x + threadIdx.x;
  if (i < N_NODES) {
    float dv = rsqrtf((float)(degdinv[i] + 1u));
    reinterpret_cast<float*>(degdinv)[i] = dv;
  }
}

__global__ __launch_bounds__(256) void scatter_kernel(
    const i32x4* __restrict__ src4, const i32x4* __restrict__ dst4,
    const float* __restrict__ dinv, const float4* __restrict__ state4,
    float* __restrict__ acc) {
  int stride = gridDim.x * blockDim.x;
  for (int e = blockIdx.x * blockDim.x + threadIdx.x; e < N_EDGES / 4; e += stride) {
    i32x4 s4 = __builtin_nontemporal_load(src4 + e);
    i32x4 d4 = __builtin_nontemporal_load(dst4 + e);
#pragma unroll
    for (int u = 0; u < 4; ++u) {
      int s = (u == 0) ? s4.x : (u == 1) ? s4.y : (u == 2) ? s4.z : s4.w;
      int d = (u == 0) ? d4.x : (u == 1) ? d4.y : (u == 2) ? d4.z : d4.w;
      float w = dinv[s] * dinv[d];
      float4 st = state4[s];
      float* base = acc + (size_t)(d >> 2) * 4;
      atomicAdd(base + 0, w * st.x);
      atomicAdd(base + 1, w * st.y);
      atomicAdd(base + 2, w * st.z);
      atomicAdd(base + 3, w * st.w);
    }
  }
}

__global__ __launch_bounds__(256) void final_kernel(
    const float4* __restrict__ state4, const float4* __restrict__ dinv4,
    const float4* __restrict__ acc4, const float* __restrict__ W1,
    const float* __restrict__ fold, const float* __restrict__ W2,
    const float* __restrict__ b2, float* __restrict__ out) {
  __shared__ float4 w1aT[32];
  __shared__ float4 wg1T[32];
  __shared__ float b1p[32];
  __shared__ float w2s[32];
  int t = threadIdx.x;
  if (t < 32) {
    w1aT[t] = make_float4(W1[t], W1[32 + t], W1[64 + t], W1[96 + t]);
    wg1T[t] = ((const float4*)fold)[t];
    b1p[t]  = fold[128 + t];
    w2s[t]  = W2[t];
  }
  __syncthreads();
  int b = blockIdx.x * blockDim.x + t;
  if (b >= N_GRAPHS) return;
  float4 s0 = state4[4 * b + 0], s1 = state4[4 * b + 1];
  float4 s2 = state4[4 * b + 2], s3 = state4[4 * b + 3];
  float4 dv = dinv4[b];
  float4 a  = acc4[b];
  float q0 = dv.x * dv.x, q1 = dv.y * dv.y, q2 = dv.z * dv.z, q3 = dv.w * dv.w;
  a.x += q0 * s0.x + q1 * s1.x + q2 * s2.x + q3 * s3.x;
  a.y += q0 * s0.y + q1 * s1.y + q2 * s2.y + q3 * s3.y;
  a.z += q0 * s0.z + q1 * s1.z + q2 * s2.z + q3 * s3.z;
  a.w += q0 * s0.w + q1 * s1.w + q2 * s2.w + q3 * s3.w;
  float4 vs;
  vs.x = s0.x + s1.x + s2.x + s3.x;
  vs.y = s0.y + s1.y + s2.y + s3.y;
  vs.z = s0.z + s1.z + s2.z + s3.z;
  vs.w = s0.w + s1.w + s2.w + s3.w;
  float accum = b2[0];
#pragma unroll
  for (int j = 0; j < 32; ++j) {
    float4 wa = w1aT[j], wg = wg1T[j];
    float h = b1p[j]
            + vs.x * wa.x + vs.y * wa.y + vs.z * wa.z + vs.w * wa.w
            + a.x * wg.x + a.y * wg.y + a.z * wg.z + a.w * wg.w;
    accum += fmaxf(h, 0.f) * w2s[j];
  }
  out[b] = accum;
}

// ================= launch =================

extern "C" void kernel_launch(void* const* d_in, const int* in_sizes, int n_in,
                              void* d_out, int out_size, void* d_ws, size_t ws_size,
                              hipStream_t stream) {
  const float* state = (const float*)d_in[0];
  const int*   ei    = (const int*)d_in[1];   // int32: [2][N_EDGES]
  const float* Wgcn  = (const float*)d_in[2];
  const float* bgcn  = (const float*)d_in[3];
  const float* W1    = (const float*)d_in[4];
  const float* b1    = (const float*)d_in[5];
  const float* W2    = (const float*)d_in[6];
  const float* b2    = (const float*)d_in[7];
  float* out = (float*)d_out;

  char* ws = (char*)d_ws;
  const size_t MB = 1024u * 1024u;

  const size_t recs_bytes = (size_t)NBIN * BINCAP * 8;            // 112,164,864
  const size_t dinv_off   = recs_bytes;
  const size_t dsi_off    = dinv_off + (size_t)N_NODES * 4;       // 16B-aligned
  const size_t gcur_off_d = (dsi_off + (size_t)N_NODES * 16 + 255) & ~(size_t)255;
  const size_t need_dsi   = gcur_off_d + 4096 + 1024;             // ~192.2 MB
  const size_t gcur_off_n = (dsi_off + 255) & ~(size_t)255;
  const size_t need_nodsi = gcur_off_n + 4096 + 1024;             // ~128.2 MB

  const size_t scat_smem = (size_t)NBIN * LCAP * 8 + NBIN * 4;    // 64,548 B
  const size_t red_smem  = 2 * NPBIN * 4;                         // 64 KiB

  if (ws_size >= need_nodsi) {
    bool use_dsi = (ws_size >= need_dsi);
    u64*      recs = (u64*)ws;
    float*    dinv = (float*)(ws + dinv_off);
    float4*   dsi4 = (float4*)(ws + dsi_off);
    unsigned* gcur = (unsigned*)(ws + (use_dsi ? gcur_off_d : gcur_off_n));
    float*    fold = (float*)((char*)gcur + 4096);

    (void)hipMemsetAsync(gcur, 0, 4096, stream);
    fold_kernel<<<1, 128, 0, stream>>>(Wgcn, bgcn, W1, b1, fold);
    binscatter_kernel<<<SBLOCKS, 512, scat_smem, stream>>>(
        ei, ei + N_EDGES, gcur, recs);
    if (use_dsi) {
      bindeg_kernel<true><<<NBIN, 512, 0, stream>>>(
          recs, gcur, (const float4*)state, dinv, dsi4);
      binreduce_kernel<true><<<NBIN, 512, red_smem, stream>>>(
          recs, gcur, dinv, dsi4, (const float4*)state, W1, fold, W2, b2, out);
    } else {
      bindeg_kernel<false><<<NBIN, 512, 0, stream>>>(
          recs, gcur, (const float4*)state, dinv, dsi4);
      binreduce_kernel<false><<<NBIN, 512, red_smem, stream>>>(
          recs, gcur, dinv, dsi4, (const float4*)state, W1, fold, W2, b2, out);
    }
    return;
  }

  // emergency fallback (33 MB): round-3 atomic-scatter path
  {
    unsigned* deg  = (unsigned*)ws;
    float*    acc  = (float*)(ws + 16 * MB);
    float*    fold = (float*)(ws + 32 * MB);
    (void)hipMemsetAsync(d_ws, 0, 32 * MB + 1024, stream);
    fold_kernel<<<1, 128, 0, stream>>>(Wgcn, bgcn, W1, b1, fold);
    deg_kernel<<<4096, 256, 0, stream>>>((const i32x4*)(ei + N_EDGES), deg);
    dinv_kernel<<<(N_NODES + 255) / 256, 256, 0, stream>>>(deg);
    scatter_kernel<<<8192, 256, 0, stream>>>(
        (const i32x4*)ei, (const i32x4*)(ei + N_EDGES),
        (const float*)deg, (const float4*)state, acc);
    final_kernel<<<(N_GRAPHS + 255) / 256, 256, 0, stream>>>(
        (const float4*)state, (const float4*)deg, (const float4*)acc,
        W1, fold, W2, b2, out);
  }
}

// Round 7
// 559.708 us; speedup vs baseline: 5.1438x; 1.0133x over previous
//
#include <hip/hip_runtime.h>

typedef unsigned long long u64;
typedef __attribute__((ext_vector_type(4))) int i32x4;

#define N_NODES   4000000
#define N_EDGES   12000000
#define N_GRAPHS  1000000

// ---- bin-path params ----
#define NBIN      977        // bins of 1024 dst-graphs (ceil(1e6/1024))
#define GPBIN     1024
#define NPBIN     4096       // nodes per bin
#define BINCAP    14336      // recs/bin capacity (mean 12288, +18 sigma)
#define LCAP      8          // LDS staging recs per bin
#define SBLOCKS   512
#define SEPB      23438      // ceil(12M/512)

// ================= shared =================

__global__ __launch_bounds__(256) void fold_kernel(
    const float* __restrict__ Wgcn, const float* __restrict__ bgcn,
    const float* __restrict__ W1, const float* __restrict__ b1,
    float* __restrict__ fold) {
  int t = threadIdx.x;
  if (t < 128) {
    int j = t >> 2, c = t & 3;
    float s = 0.f;
    for (int k = 0; k < 32; ++k) s += Wgcn[c * 32 + k] * W1[(4 + k) * 32 + j];
    fold[j * 4 + c] = s;                    // Wg1T[j][c]
  }
  if (t < 32) {
    float s = 0.f;
    for (int k = 0; k < 32; ++k) s += bgcn[k] * W1[(4 + k) * 32 + t];
    fold[128 + t] = b1[t] + 4.0f * s;       // b1p[j]
  }
}

// ================= bin path =================

__global__ __launch_bounds__(512) void binscatter_kernel(
    const int* __restrict__ src, const int* __restrict__ dst,
    unsigned* __restrict__ gcur, u64* __restrict__ recs) {
  extern __shared__ char smem[];
  u64* buf = (u64*)smem;                               // [NBIN*LCAP]
  unsigned* cnt = (unsigned*)(smem + NBIN * LCAP * 8); // [NBIN]
  int t = threadIdx.x;
  for (int i = t; i < NBIN; i += 512) cnt[i] = 0;
  __syncthreads();
  const int base = blockIdx.x * SEPB;
  const int limit = min(SEPB, N_EDGES - base);
  const int nrounds = (limit + 1023) / 1024;

  int cs0 = 0, cd0 = 0, cs1 = 0, cd1 = 0;
  {
    int off = t;
    if (off < limit) { cs0 = __builtin_nontemporal_load(src + base + off);
                       cd0 = __builtin_nontemporal_load(dst + base + off); }
    off += 512;
    if (off < limit) { cs1 = __builtin_nontemporal_load(src + base + off);
                       cd1 = __builtin_nontemporal_load(dst + base + off); }
  }
  for (int r = 0; r < nrounds; ++r) {
    int ns0 = 0, nd0 = 0, ns1 = 0, nd1 = 0;
    if (r + 1 < nrounds) {
      int off = (r + 1) * 1024 + t;
      if (off < limit) { ns0 = __builtin_nontemporal_load(src + base + off);
                         nd0 = __builtin_nontemporal_load(dst + base + off); }
      off += 512;
      if (off < limit) { ns1 = __builtin_nontemporal_load(src + base + off);
                         nd1 = __builtin_nontemporal_load(dst + base + off); }
    }
    int off = r * 1024 + t;
#pragma unroll
    for (int k = 0; k < 2; ++k) {
      int o = off + k * 512;
      if (o < limit) {
        int s = k ? cs1 : cs0;
        int d = k ? cd1 : cd0;
        unsigned graph = (unsigned)d >> 2;
        unsigned bin   = graph >> 10;
        unsigned glo   = graph & 1023u;
        u64 rec = ((u64)glo << 32) | ((u64)((unsigned)s << 2) | (unsigned)(d & 3));
        unsigned idx = atomicAdd(&cnt[bin], 1u);
        if (idx < LCAP) buf[bin * LCAP + idx] = rec;
        else {  // rare spill
          unsigned p = atomicAdd(&gcur[bin], 1u);
          if (p < BINCAP) recs[(size_t)bin * BINCAP + p] = rec;
        }
      }
    }
    __syncthreads();
    bool fin = (r == nrounds - 1);
    for (int bin = t; bin < NBIN; bin += 512) {
      unsigned c = cnt[bin]; if (c > LCAP) c = LCAP;
      unsigned n = fin ? c : (c & ~3u);   // multiples of 4 recs = 32B bursts
      if (n) {
        unsigned pos = atomicAdd(&gcur[bin], n);
        if (pos + n <= BINCAP) {
          u64* dp = recs + (size_t)bin * BINCAP + pos;
          for (unsigned i = 0; i < n; ++i) dp[i] = buf[bin * LCAP + i];
        }
      }
      unsigned rem = c - n;
      for (unsigned i = 0; i < rem; ++i) buf[bin * LCAP + i] = buf[bin * LCAP + n + i];
      cnt[bin] = rem;
    }
    __syncthreads();
    cs0 = ns0; cd0 = nd0; cs1 = ns1; cd1 = nd1;
  }
}

template <bool DSI>
__global__ __launch_bounds__(512) void bindeg_kernel(
    const u64* __restrict__ recs, const unsigned* __restrict__ gcur,
    const float4* __restrict__ state4,
    float* __restrict__ dinv, float4* __restrict__ dsi4) {
  __shared__ unsigned degL[NPBIN];
  int t = threadIdx.x, bin = blockIdx.x;
  for (int i = t; i < NPBIN; i += 512) degL[i] = 0;
  __syncthreads();
  unsigned n = gcur[bin]; if (n > BINCAP) n = BINCAP;
  const u64* rp = recs + (size_t)bin * BINCAP;
  for (unsigned i = t; i < n; i += 512) {
    u64 v = __builtin_nontemporal_load(rp + i);
    unsigned lo = (unsigned)v, glo = (unsigned)(v >> 32);
    atomicAdd(&degL[glo * 4 + (lo & 3u)], 1u);
  }
  __syncthreads();
  int nb = bin * NPBIN;
  for (int i = t; i < NPBIN; i += 512) {
    int node = nb + i;
    if (node < N_NODES) {
      float dv = rsqrtf((float)(degL[i] + 1u));
      dinv[node] = dv;
      if (DSI) {
        float4 s = state4[node];
        dsi4[node] = make_float4(dv * s.x, dv * s.y, dv * s.z, dv * s.w);
      }
    }
  }
}

template <bool DSI>
__global__ __launch_bounds__(512, 8) void binreduce_kernel(
    const u64* __restrict__ recs, const unsigned* __restrict__ gcur,
    const float* __restrict__ dinv, const float4* __restrict__ dsi4,
    const float4* __restrict__ state4,
    const float* __restrict__ W1, const float* __restrict__ fold,
    const float* __restrict__ W2, const float* __restrict__ b2,
    float* __restrict__ out) {
  extern __shared__ float dynsm[];
  float* dinvL = dynsm;           // [NPBIN]
  float* accL  = dynsm + NPBIN;   // [NPBIN]
  __shared__ float4 w1aT[32], wg1T[32];
  __shared__ float b1p[32], w2s[32];
  int t = threadIdx.x, bin = blockIdx.x;
  if (t < 32) {
    w1aT[t] = make_float4(W1[t], W1[32 + t], W1[64 + t], W1[96 + t]);
    wg1T[t] = ((const float4*)fold)[t];
    b1p[t]  = fold[128 + t];
    w2s[t]  = W2[t];
  }
  int nb = bin * NPBIN;
  for (int i = t; i < NPBIN; i += 512) {
    int node = nb + i;
    dinvL[i] = (node < N_NODES) ? dinv[node] : 0.f;
    accL[i]  = 0.f;
  }
  __syncthreads();
  unsigned n = gcur[bin]; if (n > BINCAP) n = BINCAP;
  const u64* rp = recs + (size_t)bin * BINCAP;
  unsigned q = n >> 2;
  for (unsigned i = t; i < q; i += 512) {
    u64 v0 = __builtin_nontemporal_load(rp + i);
    u64 v1 = __builtin_nontemporal_load(rp + i + q);
    u64 v2 = __builtin_nontemporal_load(rp + i + 2 * q);
    u64 v3 = __builtin_nontemporal_load(rp + i + 3 * q);
    unsigned lo0 = (unsigned)v0, g0 = (unsigned)(v0 >> 32);
    unsigned lo1 = (unsigned)v1, g1 = (unsigned)(v1 >> 32);
    unsigned lo2 = (unsigned)v2, g2 = (unsigned)(v2 >> 32);
    unsigned lo3 = (unsigned)v3, g3 = (unsigned)(v3 >> 32);
    unsigned s0 = lo0 >> 2, s1 = lo1 >> 2, s2 = lo2 >> 2, s3 = lo3 >> 2;
    float4 m0, m1, m2, m3;
    float w0 = dinvL[g0 * 4 + (lo0 & 3u)];
    float w1 = dinvL[g1 * 4 + (lo1 & 3u)];
    float w2 = dinvL[g2 * 4 + (lo2 & 3u)];
    float w3 = dinvL[g3 * 4 + (lo3 & 3u)];
    if (DSI) {
      m0 = dsi4[s0]; m1 = dsi4[s1]; m2 = dsi4[s2]; m3 = dsi4[s3];
    } else {
      m0 = state4[s0]; m1 = state4[s1]; m2 = state4[s2]; m3 = state4[s3];
      w0 *= dinv[s0]; w1 *= dinv[s1]; w2 *= dinv[s2]; w3 *= dinv[s3];
    }
    float* a0 = accL + g0 * 4;
    atomicAdd(a0 + 0, w0 * m0.x); atomicAdd(a0 + 1, w0 * m0.y);
    atomicAdd(a0 + 2, w0 * m0.z); atomicAdd(a0 + 3, w0 * m0.w);
    float* a1 = accL + g1 * 4;
    atomicAdd(a1 + 0, w1 * m1.x); atomicAdd(a1 + 1, w1 * m1.y);
    atomicAdd(a1 + 2, w1 * m1.z); atomicAdd(a1 + 3, w1 * m1.w);
    float* a2 = accL + g2 * 4;
    atomicAdd(a2 + 0, w2 * m2.x); atomicAdd(a2 + 1, w2 * m2.y);
    atomicAdd(a2 + 2, w2 * m2.z); atomicAdd(a2 + 3, w2 * m2.w);
    float* a3 = accL + g3 * 4;
    atomicAdd(a3 + 0, w3 * m3.x); atomicAdd(a3 + 1, w3 * m3.y);
    atomicAdd(a3 + 2, w3 * m3.z); atomicAdd(a3 + 3, w3 * m3.w);
  }
  unsigned rem = n & 3u;
  if ((unsigned)t < rem) {
    u64 v = rp[4 * q + t];
    unsigned lo = (unsigned)v, g = (unsigned)(v >> 32);
    unsigned s = lo >> 2;
    float w = dinvL[g * 4 + (lo & 3u)];
    float4 m;
    if (DSI) { m = dsi4[s]; }
    else { m = state4[s]; w *= dinv[s]; }
    float* a = accL + g * 4;
    atomicAdd(a + 0, w * m.x); atomicAdd(a + 1, w * m.y);
    atomicAdd(a + 2, w * m.z); atomicAdd(a + 3, w * m.w);
  }
  __syncthreads();
  for (int gi = t; gi < GPBIN; gi += 512) {
    int g = bin * GPBIN + gi;
    if (g >= N_GRAPHS) break;
    float4 s0 = state4[4 * g + 0], s1 = state4[4 * g + 1];
    float4 s2 = state4[4 * g + 2], s3 = state4[4 * g + 3];
    float d0 = dinvL[gi * 4 + 0], d1 = dinvL[gi * 4 + 1];
    float d2 = dinvL[gi * 4 + 2], d3 = dinvL[gi * 4 + 3];
    float q0 = d0 * d0, q1 = d1 * d1, q2 = d2 * d2, q3 = d3 * d3;
    float ax = accL[gi * 4 + 0] + q0 * s0.x + q1 * s1.x + q2 * s2.x + q3 * s3.x;
    float ay = accL[gi * 4 + 1] + q0 * s0.y + q1 * s1.y + q2 * s2.y + q3 * s3.y;
    float az = accL[gi * 4 + 2] + q0 * s0.z + q1 * s1.z + q2 * s2.z + q3 * s3.z;
    float aw = accL[gi * 4 + 3] + q0 * s0.w + q1 * s1.w + q2 * s2.w + q3 * s3.w;
    float vx = s0.x + s1.x + s2.x + s3.x;
    float vy = s0.y + s1.y + s2.y + s3.y;
    float vz = s0.z + s1.z + s2.z + s3.z;
    float vw = s0.w + s1.w + s2.w + s3.w;
    float accum = b2[0];
#pragma unroll 4
    for (int j = 0; j < 32; ++j) {
      float4 wa = w1aT[j], wg = wg1T[j];
      float h = b1p[j]
              + vx * wa.x + vy * wa.y + vz * wa.z + vw * wa.w
              + ax * wg.x + ay * wg.y + az * wg.z + aw * wg.w;
      accum += fmaxf(h, 0.f) * w2s[j];
    }
    out[g] = accum;
  }
}

// ================= round-3 fallback =================

__global__ __launch_bounds__(256) void deg_kernel(
    const i32x4* __restrict__ dst4, unsigned* __restrict__ deg) {
  int stride = gridDim.x * blockDim.x;
  for (int e = blockIdx.x * blockDim.x + threadIdx.x; e < N_EDGES / 4; e += stride) {
    i32x4 d = __builtin_nontemporal_load(dst4 + e);
    atomicAdd(&deg[d.x], 1u);
    atomicAdd(&deg[d.y], 1u);
    atomicAdd(&deg[d.z], 1u);
    atomicAdd(&deg[d.w], 1u);
  }
}

__global__ __launch_bounds__(256) void dinv_kernel(unsigned* __restrict__ degdinv) {
  int i = blockIdx.x * blockDim.x + threadIdx.x;
  if (i < N_NODES) {
    float dv = rsqrtf((float)(degdinv[i] + 1u));
    reinterpret_cast<float*>(degdinv)[i] = dv;
  }
}

__global__ __launch_bounds__(256) void scatter_kernel(
    const i32x4* __restrict__ src4, const i32x4* __restrict__ dst4,
    const float* __restrict__ dinv, const float4* __restrict__ state4,
    float* __restrict__ acc) {
  int stride = gridDim.x * blockDim.x;
  for (int e = blockIdx.x * blockDim.x + threadIdx.x; e < N_EDGES / 4; e += stride) {
    i32x4 s4 = __builtin_nontemporal_load(src4 + e);
    i32x4 d4 = __builtin_nontemporal_load(dst4 + e);
#pragma unroll
    for (int u = 0; u < 4; ++u) {
      int s = (u == 0) ? s4.x : (u == 1) ? s4.y : (u == 2) ? s4.z : s4.w;
      int d = (u == 0) ? d4.x : (u == 1) ? d4.y : (u == 2) ? d4.z : d4.w;
      float w = dinv[s] * dinv[d];
      float4 st = state4[s];
      float* base = acc + (size_t)(d >> 2) * 4;
      atomicAdd(base + 0, w * st.x);
      atomicAdd(base + 1, w * st.y);
      atomicAdd(base + 2, w * st.z);
      atomicAdd(base + 3, w * st.w);
    }
  }
}

__global__ __launch_bounds__(256) void final_kernel(
    const float4* __restrict__ state4, const float4* __restrict__ dinv4,
    const float4* __restrict__ acc4, const float* __restrict__ W1,
    const float* __restrict__ fold, const float* __restrict__ W2,
    const float* __restrict__ b2, float* __restrict__ out) {
  __shared__ float4 w1aT[32];
  __shared__ float4 wg1T[32];
  __shared__ float b1p[32];
  __shared__ float w2s[32];
  int t = threadIdx.x;
  if (t < 32) {
    w1aT[t] = make_float4(W1[t], W1[32 + t], W1[64 + t], W1[96 + t]);
    wg1T[t] = ((const float4*)fold)[t];
    b1p[t]  = fold[128 + t];
    w2s[t]  = W2[t];
  }
  __syncthreads();
  int b = blockIdx.x * blockDim.x + t;
  if (b >= N_GRAPHS) return;
  float4 s0 = state4[4 * b + 0], s1 = state4[4 * b + 1];
  float4 s2 = state4[4 * b + 2], s3 = state4[4 * b + 3];
  float4 dv = dinv4[b];
  float4 a  = acc4[b];
  float q0 = dv.x * dv.x, q1 = dv.y * dv.y, q2 = dv.z * dv.z, q3 = dv.w * dv.w;
  a.x += q0 * s0.x + q1 * s1.x + q2 * s2.x + q3 * s3.x;
  a.y += q0 * s0.y + q1 * s1.y + q2 * s2.y + q3 * s3.y;
  a.z += q0 * s0.z + q1 * s1.z + q2 * s2.z + q3 * s3.z;
  a.w += q0 * s0.w + q1 * s1.w + q2 * s2.w + q3 * s3.w;
  float4 vs;
  vs.x = s0.x + s1.x + s2.x + s3.x;
  vs.y = s0.y + s1.y + s2.y + s3.y;
  vs.z = s0.z + s1.z + s2.z + s3.z;
  vs.w = s0.w + s1.w + s2.w + s3.w;
  float accum = b2[0];
#pragma unroll
  for (int j = 0; j < 32; ++j) {
    float4 wa = w1aT[j], wg = wg1T[j];
    float h = b1p[j]
            + vs.x * wa.x + vs.y * wa.y + vs.z * wa.z + vs.w * wa.w
            + a.x * wg.x + a.y * wg.y + a.z * wg.z + a.w * wg.w;
    accum += fmaxf(h, 0.f) * w2s[j];
  }
  out[b] = accum;
}

// ================= launch =================

extern "C" void kernel_launch(void* const* d_in, const int* in_sizes, int n_in,
                              void* d_out, int out_size, void* d_ws, size_t ws_size,
                              hipStream_t stream) {
  const float* state = (const float*)d_in[0];
  const int*   ei    = (const int*)d_in[1];   // int32: [2][N_EDGES]
  const float* Wgcn  = (const float*)d_in[2];
  const float* bgcn  = (const float*)d_in[3];
  const float* W1    = (const float*)d_in[4];
  const float* b1    = (const float*)d_in[5];
  const float* W2    = (const float*)d_in[6];
  const float* b2    = (const float*)d_in[7];
  float* out = (float*)d_out;

  char* ws = (char*)d_ws;
  const size_t MB = 1024u * 1024u;

  const size_t recs_bytes = (size_t)NBIN * BINCAP * 8;            // 112,050,176
  const size_t dinv_off   = recs_bytes;
  const size_t dsi_off    = dinv_off + (size_t)N_NODES * 4;
  const size_t gcur_off_d = (dsi_off + (size_t)N_NODES * 16 + 255) & ~(size_t)255;
  const size_t need_dsi   = gcur_off_d + 8192 + 1024;
  const size_t gcur_off_n = (dsi_off + 255) & ~(size_t)255;
  const size_t need_nodsi = gcur_off_n + 8192 + 1024;

  const size_t scat_smem = (size_t)NBIN * LCAP * 8 + NBIN * 4;    // 66,436 B
  const size_t red_smem  = 2 * NPBIN * 4;                         // 32 KiB

  if (ws_size >= need_nodsi) {
    bool use_dsi = (ws_size >= need_dsi);
    u64*      recs = (u64*)ws;
    float*    dinv = (float*)(ws + dinv_off);
    float4*   dsi4 = (float4*)(ws + dsi_off);
    unsigned* gcur = (unsigned*)(ws + (use_dsi ? gcur_off_d : gcur_off_n));
    float*    fold = (float*)((char*)gcur + 8192);

    (void)hipMemsetAsync(gcur, 0, 8192, stream);
    fold_kernel<<<1, 128, 0, stream>>>(Wgcn, bgcn, W1, b1, fold);
    binscatter_kernel<<<SBLOCKS, 512, scat_smem, stream>>>(
        ei, ei + N_EDGES, gcur, recs);
    if (use_dsi) {
      bindeg_kernel<true><<<NBIN, 512, 0, stream>>>(
          recs, gcur, (const float4*)state, dinv, dsi4);
      binreduce_kernel<true><<<NBIN, 512, red_smem, stream>>>(
          recs, gcur, dinv, dsi4, (const float4*)state, W1, fold, W2, b2, out);
    } else {
      bindeg_kernel<false><<<NBIN, 512, 0, stream>>>(
          recs, gcur, (const float4*)state, dinv, dsi4);
      binreduce_kernel<false><<<NBIN, 512, red_smem, stream>>>(
          recs, gcur, dinv, dsi4, (const float4*)state, W1, fold, W2, b2, out);
    }
    return;
  }

  // emergency fallback (33 MB): round-3 atomic-scatter path
  {
    unsigned* deg  = (unsigned*)ws;
    float*    acc  = (float*)(ws + 16 * MB);
    float*    fold = (float*)(ws + 32 * MB);
    (void)hipMemsetAsync(d_ws, 0, 32 * MB + 1024, stream);
    fold_kernel<<<1, 128, 0, stream>>>(Wgcn, bgcn, W1, b1, fold);
    deg_kernel<<<4096, 256, 0, stream>>>((const i32x4*)(ei + N_EDGES), deg);
    dinv_kernel<<<(N_NODES + 255) / 256, 256, 0, stream>>>(deg);
    scatter_kernel<<<8192, 256, 0, stream>>>(
        (const i32x4*)ei, (const i32x4*)(ei + N_EDGES),
        (const float*)deg, (const float4*)state, acc);
    final_kernel<<<(N_GRAPHS + 255) / 256, 256, 0, stream>>>(
        (const float4*)state, (const float4*)deg, (const float4*)acc,
        W1, fold, W2, b2, out);
  }
}

// Round 8
// 492.204 us; speedup vs baseline: 5.8493x; 1.1371x over previous
//
#include <hip/hip_runtime.h>

typedef unsigned long long u64;
typedef __attribute__((ext_vector_type(4))) int i32x4;
typedef __attribute__((ext_vector_type(2))) unsigned long long u64x2;

#define N_NODES   4000000
#define N_EDGES   12000000
#define N_GRAPHS  1000000

// ---- bin-path params ----
#define NBIN      977        // bins of 1024 dst-graphs (ceil(1e6/1024))
#define GPBIN     1024
#define NPBIN     4096       // nodes per bin
#define BINCAP    14336      // recs/bin capacity (mean 12288, +18 sigma)
#define LCAP      8          // LDS staging recs per bin
#define SBLOCKS   512
#define SEPB      23440      // multiple of 16; 512*23440 >= 12M

// ================= shared =================

__global__ __launch_bounds__(256) void fold_kernel(
    const float* __restrict__ Wgcn, const float* __restrict__ bgcn,
    const float* __restrict__ W1, const float* __restrict__ b1,
    float* __restrict__ fold) {
  int t = threadIdx.x;
  if (t < 128) {
    int j = t >> 2, c = t & 3;
    float s = 0.f;
    for (int k = 0; k < 32; ++k) s += Wgcn[c * 32 + k] * W1[(4 + k) * 32 + j];
    fold[j * 4 + c] = s;                    // Wg1T[j][c]
  }
  if (t < 32) {
    float s = 0.f;
    for (int k = 0; k < 32; ++k) s += bgcn[k] * W1[(4 + k) * 32 + t];
    fold[128 + t] = b1[t] + 4.0f * s;       // b1p[j]
  }
}

// ================= bin path =================

__global__ __launch_bounds__(512) void binscatter_kernel(
    const int* __restrict__ src, const int* __restrict__ dst,
    unsigned* __restrict__ gcur, u64* __restrict__ recs) {
  extern __shared__ char smem[];
  u64* buf = (u64*)smem;                               // [NBIN*LCAP]
  unsigned* cnt = (unsigned*)(smem + NBIN * LCAP * 8); // [NBIN]
  int t = threadIdx.x;
  for (int i = t; i < NBIN; i += 512) cnt[i] = 0;
  __syncthreads();
  const int base = blockIdx.x * SEPB;
  const int limit = min(SEPB, N_EDGES - base);   // multiple of 16
  const int V = limit >> 2;                      // i32x4 vectors in this block
  const int nrounds = (V + 511) / 512;
  const i32x4* src4 = (const i32x4*)(src + base);
  const i32x4* dst4 = (const i32x4*)(dst + base);

  i32x4 cs = {0, 0, 0, 0}, cd = {0, 0, 0, 0};
  if (t < V) { cs = __builtin_nontemporal_load(src4 + t);
               cd = __builtin_nontemporal_load(dst4 + t); }
  for (int r = 0; r < nrounds; ++r) {
    i32x4 ns = {0, 0, 0, 0}, nd = {0, 0, 0, 0};
    int nidx = (r + 1) * 512 + t;
    if (r + 1 < nrounds && nidx < V) {
      ns = __builtin_nontemporal_load(src4 + nidx);
      nd = __builtin_nontemporal_load(dst4 + nidx);
    }
    int idx = r * 512 + t;
    if (idx < V) {
#pragma unroll
      for (int k = 0; k < 4; ++k) {
        int s = cs[k];
        int d = cd[k];
        unsigned graph = (unsigned)d >> 2;
        unsigned bin   = graph >> 10;
        unsigned glo   = graph & 1023u;
        u64 rec = ((u64)glo << 32) | ((u64)((unsigned)s << 2) | (unsigned)(d & 3));
        unsigned pos = atomicAdd(&cnt[bin], 1u);
        if (pos < LCAP) buf[bin * LCAP + pos] = rec;
        else {  // rare spill
          unsigned p = atomicAdd(&gcur[bin], 1u);
          if (p < BINCAP) recs[(size_t)bin * BINCAP + p] = rec;
        }
      }
    }
    __syncthreads();
    bool fin = (r == nrounds - 1);
    for (int bin = t; bin < NBIN; bin += 512) {
      unsigned c = cnt[bin]; if (c > LCAP) c = LCAP;
      unsigned n = fin ? c : (c & ~3u);   // 32B bursts
      if (n) {
        unsigned pos = atomicAdd(&gcur[bin], n);
        if (pos + n <= BINCAP) {
          u64* dp = recs + (size_t)bin * BINCAP + pos;
#pragma unroll 4
          for (unsigned i = 0; i < n; ++i) dp[i] = buf[bin * LCAP + i];
        }
      }
      unsigned rem = c - n;
      for (unsigned i = 0; i < rem; ++i) buf[bin * LCAP + i] = buf[bin * LCAP + n + i];
      cnt[bin] = rem;
    }
    __syncthreads();
    cs = ns; cd = nd;
  }
}

template <bool DSI>
__global__ __launch_bounds__(512) void bindeg_kernel(
    const u64* __restrict__ recs, const unsigned* __restrict__ gcur,
    const float4* __restrict__ state4,
    float* __restrict__ dinv, float4* __restrict__ dsi4) {
  __shared__ unsigned degL[NPBIN];
  int t = threadIdx.x, bin = blockIdx.x;
  for (int i = t; i < NPBIN; i += 512) degL[i] = 0;
  __syncthreads();
  unsigned n = gcur[bin]; if (n > BINCAP) n = BINCAP;
  const u64* rp = recs + (size_t)bin * BINCAP;
  const u64x2* rv = (const u64x2*)rp;
  unsigned nv = n >> 1;
  for (unsigned i = t; i < nv; i += 512) {
    u64x2 p = __builtin_nontemporal_load(rv + i);
    unsigned lo0 = (unsigned)p.x, g0 = (unsigned)(p.x >> 32);
    unsigned lo1 = (unsigned)p.y, g1 = (unsigned)(p.y >> 32);
    atomicAdd(&degL[g0 * 4 + (lo0 & 3u)], 1u);
    atomicAdd(&degL[g1 * 4 + (lo1 & 3u)], 1u);
  }
  if ((n & 1u) && t == 0) {
    u64 v = rp[n - 1];
    atomicAdd(&degL[((unsigned)(v >> 32)) * 4 + ((unsigned)v & 3u)], 1u);
  }
  __syncthreads();
  int nb = bin * NPBIN;
  for (int i = t; i < NPBIN; i += 512) {
    int node = nb + i;
    if (node < N_NODES) {
      float dv = rsqrtf((float)(degL[i] + 1u));
      dinv[node] = dv;
      if (DSI) {
        float4 s = state4[node];
        dsi4[node] = make_float4(dv * s.x, dv * s.y, dv * s.z, dv * s.w);
      }
    }
  }
}

template <bool DSI>
__global__ __launch_bounds__(512, 4) void binreduce_kernel(
    const u64* __restrict__ recs, const unsigned* __restrict__ gcur,
    const float* __restrict__ dinv, const float4* __restrict__ dsi4,
    const float4* __restrict__ state4,
    const float* __restrict__ W1, const float* __restrict__ fold,
    const float* __restrict__ W2, const float* __restrict__ b2,
    float* __restrict__ out) {
  extern __shared__ float dynsm[];
  float* dinvL = dynsm;           // [NPBIN]
  float* accL  = dynsm + NPBIN;   // [NPBIN]
  __shared__ float4 w1aT[32], wg1T[32];
  __shared__ float b1p[32], w2s[32];
  int t = threadIdx.x, bin = blockIdx.x;
  if (t < 32) {
    w1aT[t] = make_float4(W1[t], W1[32 + t], W1[64 + t], W1[96 + t]);
    wg1T[t] = ((const float4*)fold)[t];
    b1p[t]  = fold[128 + t];
    w2s[t]  = W2[t];
  }
  int nb = bin * NPBIN;
  for (int i = t; i < NPBIN; i += 512) {
    int node = nb + i;
    dinvL[i] = (node < N_NODES) ? dinv[node] : 0.f;
    accL[i]  = 0.f;
  }
  __syncthreads();
  unsigned n = gcur[bin]; if (n > BINCAP) n = BINCAP;
  const u64* rp = recs + (size_t)bin * BINCAP;
  const u64x2* rv = (const u64x2*)rp;
  unsigned m = n >> 3;   // iterations; 4 vector streams of m elements = 8m recs
  for (unsigned i = t; i < m; i += 512) {
    u64x2 p0 = __builtin_nontemporal_load(rv + i);
    u64x2 p1 = __builtin_nontemporal_load(rv + i + m);
    u64x2 p2 = __builtin_nontemporal_load(rv + i + 2 * m);
    u64x2 p3 = __builtin_nontemporal_load(rv + i + 3 * m);
    u64 r0 = p0.x, r1 = p0.y, r2 = p1.x, r3 = p1.y;
    u64 r4 = p2.x, r5 = p2.y, r6 = p3.x, r7 = p3.y;
    unsigned lo0 = (unsigned)r0, g0 = (unsigned)(r0 >> 32), s0 = lo0 >> 2;
    unsigned lo1 = (unsigned)r1, g1 = (unsigned)(r1 >> 32), s1 = lo1 >> 2;
    unsigned lo2 = (unsigned)r2, g2 = (unsigned)(r2 >> 32), s2 = lo2 >> 2;
    unsigned lo3 = (unsigned)r3, g3 = (unsigned)(r3 >> 32), s3 = lo3 >> 2;
    unsigned lo4 = (unsigned)r4, g4 = (unsigned)(r4 >> 32), s4 = lo4 >> 2;
    unsigned lo5 = (unsigned)r5, g5 = (unsigned)(r5 >> 32), s5 = lo5 >> 2;
    unsigned lo6 = (unsigned)r6, g6 = (unsigned)(r6 >> 32), s6 = lo6 >> 2;
    unsigned lo7 = (unsigned)r7, g7 = (unsigned)(r7 >> 32), s7 = lo7 >> 2;
    float4 m0, m1, m2, m3, m4, m5, m6, m7;
    float w0 = dinvL[g0 * 4 + (lo0 & 3u)];
    float w1 = dinvL[g1 * 4 + (lo1 & 3u)];
    float w2 = dinvL[g2 * 4 + (lo2 & 3u)];
    float w3 = dinvL[g3 * 4 + (lo3 & 3u)];
    float w4 = dinvL[g4 * 4 + (lo4 & 3u)];
    float w5 = dinvL[g5 * 4 + (lo5 & 3u)];
    float w6 = dinvL[g6 * 4 + (lo6 & 3u)];
    float w7 = dinvL[g7 * 4 + (lo7 & 3u)];
    if (DSI) {
      m0 = dsi4[s0]; m1 = dsi4[s1]; m2 = dsi4[s2]; m3 = dsi4[s3];
      m4 = dsi4[s4]; m5 = dsi4[s5]; m6 = dsi4[s6]; m7 = dsi4[s7];
    } else {
      m0 = state4[s0]; m1 = state4[s1]; m2 = state4[s2]; m3 = state4[s3];
      m4 = state4[s4]; m5 = state4[s5]; m6 = state4[s6]; m7 = state4[s7];
      w0 *= dinv[s0]; w1 *= dinv[s1]; w2 *= dinv[s2]; w3 *= dinv[s3];
      w4 *= dinv[s4]; w5 *= dinv[s5]; w6 *= dinv[s6]; w7 *= dinv[s7];
    }
    float* a;
    a = accL + g0 * 4;
    atomicAdd(a + 0, w0 * m0.x); atomicAdd(a + 1, w0 * m0.y);
    atomicAdd(a + 2, w0 * m0.z); atomicAdd(a + 3, w0 * m0.w);
    a = accL + g1 * 4;
    atomicAdd(a + 0, w1 * m1.x); atomicAdd(a + 1, w1 * m1.y);
    atomicAdd(a + 2, w1 * m1.z); atomicAdd(a + 3, w1 * m1.w);
    a = accL + g2 * 4;
    atomicAdd(a + 0, w2 * m2.x); atomicAdd(a + 1, w2 * m2.y);
    atomicAdd(a + 2, w2 * m2.z); atomicAdd(a + 3, w2 * m2.w);
    a = accL + g3 * 4;
    atomicAdd(a + 0, w3 * m3.x); atomicAdd(a + 1, w3 * m3.y);
    atomicAdd(a + 2, w3 * m3.z); atomicAdd(a + 3, w3 * m3.w);
    a = accL + g4 * 4;
    atomicAdd(a + 0, w4 * m4.x); atomicAdd(a + 1, w4 * m4.y);
    atomicAdd(a + 2, w4 * m4.z); atomicAdd(a + 3, w4 * m4.w);
    a = accL + g5 * 4;
    atomicAdd(a + 0, w5 * m5.x); atomicAdd(a + 1, w5 * m5.y);
    atomicAdd(a + 2, w5 * m5.z); atomicAdd(a + 3, w5 * m5.w);
    a = accL + g6 * 4;
    atomicAdd(a + 0, w6 * m6.x); atomicAdd(a + 1, w6 * m6.y);
    atomicAdd(a + 2, w6 * m6.z); atomicAdd(a + 3, w6 * m6.w);
    a = accL + g7 * 4;
    atomicAdd(a + 0, w7 * m7.x); atomicAdd(a + 1, w7 * m7.y);
    atomicAdd(a + 2, w7 * m7.z); atomicAdd(a + 3, w7 * m7.w);
  }
  unsigned done = m << 3;
  unsigned rem = n - done;
  if ((unsigned)t < rem) {
    u64 v = rp[done + t];
    unsigned lo = (unsigned)v, g = (unsigned)(v >> 32);
    unsigned s = lo >> 2;
    float w = dinvL[g * 4 + (lo & 3u)];
    float4 mm;
    if (DSI) { mm = dsi4[s]; }
    else { mm = state4[s]; w *= dinv[s]; }
    float* a = accL + g * 4;
    atomicAdd(a + 0, w * mm.x); atomicAdd(a + 1, w * mm.y);
    atomicAdd(a + 2, w * mm.z); atomicAdd(a + 3, w * mm.w);
  }
  __syncthreads();
  for (int gi = t; gi < GPBIN; gi += 512) {
    int g = bin * GPBIN + gi;
    if (g >= N_GRAPHS) break;
    float4 s0 = state4[4 * g + 0], s1 = state4[4 * g + 1];
    float4 s2 = state4[4 * g + 2], s3 = state4[4 * g + 3];
    float d0 = dinvL[gi * 4 + 0], d1 = dinvL[gi * 4 + 1];
    float d2 = dinvL[gi * 4 + 2], d3 = dinvL[gi * 4 + 3];
    float q0 = d0 * d0, q1 = d1 * d1, q2 = d2 * d2, q3 = d3 * d3;
    float ax = accL[gi * 4 + 0] + q0 * s0.x + q1 * s1.x + q2 * s2.x + q3 * s3.x;
    float ay = accL[gi * 4 + 1] + q0 * s0.y + q1 * s1.y + q2 * s2.y + q3 * s3.y;
    float az = accL[gi * 4 + 2] + q0 * s0.z + q1 * s1.z + q2 * s2.z + q3 * s3.z;
    float aw = accL[gi * 4 + 3] + q0 * s0.w + q1 * s1.w + q2 * s2.w + q3 * s3.w;
    float vx = s0.x + s1.x + s2.x + s3.x;
    float vy = s0.y + s1.y + s2.y + s3.y;
    float vz = s0.z + s1.z + s2.z + s3.z;
    float vw = s0.w + s1.w + s2.w + s3.w;
    float accum = b2[0];
#pragma unroll 4
    for (int j = 0; j < 32; ++j) {
      float4 wa = w1aT[j], wg = wg1T[j];
      float h = b1p[j]
              + vx * wa.x + vy * wa.y + vz * wa.z + vw * wa.w
              + ax * wg.x + ay * wg.y + az * wg.z + aw * wg.w;
      accum += fmaxf(h, 0.f) * w2s[j];
    }
    out[g] = accum;
  }
}

// ================= round-3 fallback =================

__global__ __launch_bounds__(256) void deg_kernel(
    const i32x4* __restrict__ dst4, unsigned* __restrict__ deg) {
  int stride = gridDim.x * blockDim.x;
  for (int e = blockIdx.x * blockDim.x + threadIdx.x; e < N_EDGES / 4; e += stride) {
    i32x4 d = __builtin_nontemporal_load(dst4 + e);
    atomicAdd(&deg[d.x], 1u);
    atomicAdd(&deg[d.y], 1u);
    atomicAdd(&deg[d.z], 1u);
    atomicAdd(&deg[d.w], 1u);
  }
}

__global__ __launch_bounds__(256) void dinv_kernel(unsigned* __restrict__ degdinv) {
  int i = blockIdx.x * blockDim.x + threadIdx.x;
  if (i < N_NODES) {
    float dv = rsqrtf((float)(degdinv[i] + 1u));
    reinterpret_cast<float*>(degdinv)[i] = dv;
  }
}

__global__ __launch_bounds__(256) void scatter_kernel(
    const i32x4* __restrict__ src4, const i32x4* __restrict__ dst4,
    const float* __restrict__ dinv, const float4* __restrict__ state4,
    float* __restrict__ acc) {
  int stride = gridDim.x * blockDim.x;
  for (int e = blockIdx.x * blockDim.x + threadIdx.x; e < N_EDGES / 4; e += stride) {
    i32x4 s4 = __builtin_nontemporal_load(src4 + e);
    i32x4 d4 = __builtin_nontemporal_load(dst4 + e);
#pragma unroll
    for (int u = 0; u < 4; ++u) {
      int s = (u == 0) ? s4.x : (u == 1) ? s4.y : (u == 2) ? s4.z : s4.w;
      int d = (u == 0) ? d4.x : (u == 1) ? d4.y : (u == 2) ? d4.z : d4.w;
      float w = dinv[s] * dinv[d];
      float4 st = state4[s];
      float* base = acc + (size_t)(d >> 2) * 4;
      atomicAdd(base + 0, w * st.x);
      atomicAdd(base + 1, w * st.y);
      atomicAdd(base + 2, w * st.z);
      atomicAdd(base + 3, w * st.w);
    }
  }
}

__global__ __launch_bounds__(256) void final_kernel(
    const float4* __restrict__ state4, const float4* __restrict__ dinv4,
    const float4* __restrict__ acc4, const float* __restrict__ W1,
    const float* __restrict__ fold, const float* __restrict__ W2,
    const float* __restrict__ b2, float* __restrict__ out) {
  __shared__ float4 w1aT[32];
  __shared__ float4 wg1T[32];
  __shared__ float b1p[32];
  __shared__ float w2s[32];
  int t = threadIdx.x;
  if (t < 32) {
    w1aT[t] = make_float4(W1[t], W1[32 + t], W1[64 + t], W1[96 + t]);
    wg1T[t] = ((const float4*)fold)[t];
    b1p[t]  = fold[128 + t];
    w2s[t]  = W2[t];
  }
  __syncthreads();
  int b = blockIdx.x * blockDim.x + t;
  if (b >= N_GRAPHS) return;
  float4 s0 = state4[4 * b + 0], s1 = state4[4 * b + 1];
  float4 s2 = state4[4 * b + 2], s3 = state4[4 * b + 3];
  float4 dv = dinv4[b];
  float4 a  = acc4[b];
  float q0 = dv.x * dv.x, q1 = dv.y * dv.y, q2 = dv.z * dv.z, q3 = dv.w * dv.w;
  a.x += q0 * s0.x + q1 * s1.x + q2 * s2.x + q3 * s3.x;
  a.y += q0 * s0.y + q1 * s1.y + q2 * s2.y + q3 * s3.y;
  a.z += q0 * s0.z + q1 * s1.z + q2 * s2.z + q3 * s3.z;
  a.w += q0 * s0.w + q1 * s1.w + q2 * s2.w + q3 * s3.w;
  float4 vs;
  vs.x = s0.x + s1.x + s2.x + s3.x;
  vs.y = s0.y + s1.y + s2.y + s3.y;
  vs.z = s0.z + s1.z + s2.z + s3.z;
  vs.w = s0.w + s1.w + s2.w + s3.w;
  float accum = b2[0];
#pragma unroll
  for (int j = 0; j < 32; ++j) {
    float4 wa = w1aT[j], wg = wg1T[j];
    float h = b1p[j]
            + vs.x * wa.x + vs.y * wa.y + vs.z * wa.z + vs.w * wa.w
            + a.x * wg.x + a.y * wg.y + a.z * wg.z + a.w * wg.w;
    accum += fmaxf(h, 0.f) * w2s[j];
  }
  out[b] = accum;
}

// ================= launch =================

extern "C" void kernel_launch(void* const* d_in, const int* in_sizes, int n_in,
                              void* d_out, int out_size, void* d_ws, size_t ws_size,
                              hipStream_t stream) {
  const float* state = (const float*)d_in[0];
  const int*   ei    = (const int*)d_in[1];   // int32: [2][N_EDGES]
  const float* Wgcn  = (const float*)d_in[2];
  const float* bgcn  = (const float*)d_in[3];
  const float* W1    = (const float*)d_in[4];
  const float* b1    = (const float*)d_in[5];
  const float* W2    = (const float*)d_in[6];
  const float* b2    = (const float*)d_in[7];
  float* out = (float*)d_out;

  char* ws = (char*)d_ws;
  const size_t MB = 1024u * 1024u;

  const size_t recs_bytes = (size_t)NBIN * BINCAP * 8;            // 112,050,176
  const size_t dinv_off   = recs_bytes;
  const size_t dsi_off    = dinv_off + (size_t)N_NODES * 4;
  const size_t gcur_off_d = (dsi_off + (size_t)N_NODES * 16 + 255) & ~(size_t)255;
  const size_t need_dsi   = gcur_off_d + 8192 + 1024;
  const size_t gcur_off_n = (dsi_off + 255) & ~(size_t)255;
  const size_t need_nodsi = gcur_off_n + 8192 + 1024;

  const size_t scat_smem = (size_t)NBIN * LCAP * 8 + NBIN * 4;    // 66,436 B
  const size_t red_smem  = 2 * NPBIN * 4;                         // 32 KiB

  if (ws_size >= need_nodsi) {
    bool use_dsi = (ws_size >= need_dsi);
    u64*      recs = (u64*)ws;
    float*    dinv = (float*)(ws + dinv_off);
    float4*   dsi4 = (float4*)(ws + dsi_off);
    unsigned* gcur = (unsigned*)(ws + (use_dsi ? gcur_off_d : gcur_off_n));
    float*    fold = (float*)((char*)gcur + 8192);

    (void)hipMemsetAsync(gcur, 0, 8192, stream);
    fold_kernel<<<1, 128, 0, stream>>>(Wgcn, bgcn, W1, b1, fold);
    binscatter_kernel<<<SBLOCKS, 512, scat_smem, stream>>>(
        ei, ei + N_EDGES, gcur, recs);
    if (use_dsi) {
      bindeg_kernel<true><<<NBIN, 512, 0, stream>>>(
          recs, gcur, (const float4*)state, dinv, dsi4);
      binreduce_kernel<true><<<NBIN, 512, red_smem, stream>>>(
          recs, gcur, dinv, dsi4, (const float4*)state, W1, fold, W2, b2, out);
    } else {
      bindeg_kernel<false><<<NBIN, 512, 0, stream>>>(
          recs, gcur, (const float4*)state, dinv, dsi4);
      binreduce_kernel<false><<<NBIN, 512, red_smem, stream>>>(
          recs, gcur, dinv, dsi4, (const float4*)state, W1, fold, W2, b2, out);
    }
    return;
  }

  // emergency fallback (33 MB): round-3 atomic-scatter path
  {
    unsigned* deg  = (unsigned*)ws;
    float*    acc  = (float*)(ws + 16 * MB);
    float*    fold = (float*)(ws + 32 * MB);
    (void)hipMemsetAsync(d_ws, 0, 32 * MB + 1024, stream);
    fold_kernel<<<1, 128, 0, stream>>>(Wgcn, bgcn, W1, b1, fold);
    deg_kernel<<<4096, 256, 0, stream>>>((const i32x4*)(ei + N_EDGES), deg);
    dinv_kernel<<<(N_NODES + 255) / 256, 256, 0, stream>>>(deg);
    scatter_kernel<<<8192, 256, 0, stream>>>(
        (const i32x4*)ei, (const i32x4*)(ei + N_EDGES),
        (const float*)deg, (const float4*)state, acc);
    final_kernel<<<(N_GRAPHS + 255) / 256, 256, 0, stream>>>(
        (const float4*)state, (const float4*)deg, (const float4*)acc,
        W1, fold, W2, b2, out);
  }
}

// Round 9
// 430.195 us; speedup vs baseline: 6.6924x; 1.1441x over previous
//
#include <hip/hip_runtime.h>
#include <hip/hip_cooperative_groups.h>

namespace cg = cooperative_groups;

typedef unsigned long long u64;
typedef __attribute__((ext_vector_type(4))) int i32x4;
typedef __attribute__((ext_vector_type(2))) unsigned long long u64x2;

#define N_NODES   4000000
#define N_EDGES   12000000
#define N_GRAPHS  1000000

// ---- bin-path params ----
#define NBIN      977        // bins of 1024 dst-graphs
#define GPBIN     1024
#define NPBIN     4096       // nodes per bin
#define BINCAP    14336      // recs/bin capacity (mean 12288, +18 sigma)
#define LCAP      16         // LDS staging recs per bin
#define SBLOCKS   256
#define SEPB      46880      // 256*46880 >= 12M, multiple of 32

// ================= fold =================

__global__ __launch_bounds__(256) void fold_kernel(
    const float* __restrict__ Wgcn, const float* __restrict__ bgcn,
    const float* __restrict__ W1, const float* __restrict__ b1,
    float* __restrict__ fold) {
  int t = threadIdx.x;
  if (t < 128) {
    int j = t >> 2, c = t & 3;
    float s = 0.f;
    for (int k = 0; k < 32; ++k) s += Wgcn[c * 32 + k] * W1[(4 + k) * 32 + j];
    fold[j * 4 + c] = s;                    // Wg1T[j][c]
  }
  if (t < 32) {
    float s = 0.f;
    for (int k = 0; k < 32; ++k) s += bgcn[k] * W1[(4 + k) * 32 + t];
    fold[128 + t] = b1[t] + 4.0f * s;       // b1p[j]
  }
}

// ================= binscatter =================

__global__ __launch_bounds__(512) void binscatter_kernel(
    const int* __restrict__ src, const int* __restrict__ dst,
    unsigned* __restrict__ gcur, u64* __restrict__ recs) {
  extern __shared__ char smem[];
  u64* buf = (u64*)smem;                               // [NBIN*LCAP]
  unsigned* cnt = (unsigned*)(smem + NBIN * LCAP * 8); // [NBIN]
  int t = threadIdx.x;
  for (int i = t; i < NBIN; i += 512) cnt[i] = 0;
  __syncthreads();
  const int base = blockIdx.x * SEPB;
  const int limit = min(SEPB, N_EDGES - base);   // >0, multiple of 4
  const int V = limit >> 2;
  const i32x4* src4 = (const i32x4*)(src + base);
  const i32x4* dst4 = (const i32x4*)(dst + base);
  const int nrounds = (V + 1023) / 1024;

  i32x4 cs0 = {0,0,0,0}, cd0 = {0,0,0,0}, cs1 = {0,0,0,0}, cd1 = {0,0,0,0};
  {
    int i0 = t, i1 = t + 512;
    if (i0 < V) { cs0 = __builtin_nontemporal_load(src4 + i0);
                  cd0 = __builtin_nontemporal_load(dst4 + i0); }
    if (i1 < V) { cs1 = __builtin_nontemporal_load(src4 + i1);
                  cd1 = __builtin_nontemporal_load(dst4 + i1); }
  }
  for (int r = 0; r < nrounds; ++r) {
    i32x4 ns0 = {0,0,0,0}, nd0 = {0,0,0,0}, ns1 = {0,0,0,0}, nd1 = {0,0,0,0};
    if (r + 1 < nrounds) {
      int j0 = (r + 1) * 1024 + t, j1 = j0 + 512;
      if (j0 < V) { ns0 = __builtin_nontemporal_load(src4 + j0);
                    nd0 = __builtin_nontemporal_load(dst4 + j0); }
      if (j1 < V) { ns1 = __builtin_nontemporal_load(src4 + j1);
                    nd1 = __builtin_nontemporal_load(dst4 + j1); }
    }
    int idx0 = r * 1024 + t;
#pragma unroll
    for (int half = 0; half < 2; ++half) {
      int idx = idx0 + half * 512;
      if (idx < V) {
        i32x4 vs = half ? cs1 : cs0;
        i32x4 vd = half ? cd1 : cd0;
#pragma unroll
        for (int k = 0; k < 4; ++k) {
          int s = vs[k];
          int d = vd[k];
          unsigned graph = (unsigned)d >> 2;
          unsigned bin   = graph >> 10;
          unsigned glo   = graph & 1023u;
          u64 rec = ((u64)glo << 32) | ((u64)((unsigned)s << 2) | (unsigned)(d & 3));
          unsigned pos = atomicAdd(&cnt[bin], 1u);
          if (pos < LCAP) buf[bin * LCAP + pos] = rec;
          else {  // rare spill
            unsigned p = atomicAdd(&gcur[bin], 1u);
            if (p < BINCAP) recs[(size_t)bin * BINCAP + p] = rec;
          }
        }
      }
    }
    __syncthreads();
    bool fin = (r == nrounds - 1);
    for (int bin = t; bin < NBIN; bin += 512) {
      unsigned c = cnt[bin]; if (c > LCAP) c = LCAP;
      unsigned nn = fin ? c : (c & ~7u);   // 64B bursts
      if (nn) {
        unsigned pos = atomicAdd(&gcur[bin], nn);
        if (pos + nn <= BINCAP) {
          u64* dp = recs + (size_t)bin * BINCAP + pos;
          for (unsigned i2 = 0; i2 < nn; ++i2) dp[i2] = buf[bin * LCAP + i2];
        }
      }
      unsigned rem2 = c - nn;
      for (unsigned i2 = 0; i2 < rem2; ++i2)
        buf[bin * LCAP + i2] = buf[bin * LCAP + nn + i2];
      cnt[bin] = rem2;
    }
    __syncthreads();
    cs0 = ns0; cd0 = nd0; cs1 = ns1; cd1 = nd1;
  }
}

// ================= fused cooperative reduce =================

__global__ __launch_bounds__(512, 8) void fusedreduce_kernel(
    const u64* __restrict__ recs, const unsigned* __restrict__ gcur,
    float4* __restrict__ dsi4, const float4* __restrict__ state4,
    const float* __restrict__ W1, const float* __restrict__ fold,
    const float* __restrict__ W2, const float* __restrict__ b2,
    float* __restrict__ out) {
  extern __shared__ float dynsm[];
  unsigned* degL = (unsigned*)dynsm;   // phase1; becomes dinvL in place
  float* dinvL = dynsm;                // [NPBIN]
  float* accL  = dynsm + NPBIN;        // [NPBIN]
  __shared__ float4 w1aT[32], wg1T[32];
  __shared__ float b1p[32], w2s[32];
  int t = threadIdx.x, bin = blockIdx.x;
  if (t < 32) {
    w1aT[t] = make_float4(W1[t], W1[32 + t], W1[64 + t], W1[96 + t]);
    wg1T[t] = ((const float4*)fold)[t];
    b1p[t]  = fold[128 + t];
    w2s[t]  = W2[t];
  }
  for (int i = t; i < NPBIN; i += 512) { degL[i] = 0u; accL[i] = 0.f; }
  __syncthreads();
  unsigned n = gcur[bin]; if (n > BINCAP) n = BINCAP;
  const u64* rp = recs + (size_t)bin * BINCAP;
  // ---- phase 1: degree histogram over this bin's recs ----
  {
    const u64x2* rv = (const u64x2*)rp;
    unsigned nv = n >> 1;
    for (unsigned i = t; i < nv; i += 512) {
      u64x2 p = __builtin_nontemporal_load(rv + i);
      atomicAdd(&degL[((unsigned)(p.x >> 32)) * 4 + ((unsigned)p.x & 3u)], 1u);
      atomicAdd(&degL[((unsigned)(p.y >> 32)) * 4 + ((unsigned)p.y & 3u)], 1u);
    }
    if ((n & 1u) && t == 0) {
      u64 v = rp[n - 1];
      atomicAdd(&degL[((unsigned)(v >> 32)) * 4 + ((unsigned)v & 3u)], 1u);
    }
  }
  __syncthreads();
  int nb = bin * NPBIN;
  for (int i = t; i < NPBIN; i += 512) {
    int node = nb + i;
    float dv = rsqrtf((float)(degL[i] + 1u));  // +1 self loop
    dinvL[i] = dv;                              // in-place over degL
    if (node < N_NODES) {
      float4 s = state4[node];
      dsi4[node] = make_float4(dv * s.x, dv * s.y, dv * s.z, dv * s.w);
    }
  }
  __threadfence();
  cg::this_grid().sync();
  // ---- phase 2: gather + accumulate (round-7 proven body) ----
  unsigned q = n >> 2;
  for (unsigned i = t; i < q; i += 512) {
    u64 r0 = __builtin_nontemporal_load(rp + i);
    u64 r1 = __builtin_nontemporal_load(rp + i + q);
    u64 r2 = __builtin_nontemporal_load(rp + i + 2 * q);
    u64 r3 = __builtin_nontemporal_load(rp + i + 3 * q);
    unsigned lo0 = (unsigned)r0, g0 = (unsigned)(r0 >> 32), s0 = lo0 >> 2;
    unsigned lo1 = (unsigned)r1, g1 = (unsigned)(r1 >> 32), s1 = lo1 >> 2;
    unsigned lo2 = (unsigned)r2, g2 = (unsigned)(r2 >> 32), s2 = lo2 >> 2;
    unsigned lo3 = (unsigned)r3, g3 = (unsigned)(r3 >> 32), s3 = lo3 >> 2;
    float w0 = dinvL[g0 * 4 + (lo0 & 3u)];
    float w1 = dinvL[g1 * 4 + (lo1 & 3u)];
    float w2 = dinvL[g2 * 4 + (lo2 & 3u)];
    float w3 = dinvL[g3 * 4 + (lo3 & 3u)];
    float4 m0 = dsi4[s0], m1 = dsi4[s1], m2 = dsi4[s2], m3 = dsi4[s3];
    float* a;
    a = accL + g0 * 4;
    atomicAdd(a + 0, w0 * m0.x); atomicAdd(a + 1, w0 * m0.y);
    atomicAdd(a + 2, w0 * m0.z); atomicAdd(a + 3, w0 * m0.w);
    a = accL + g1 * 4;
    atomicAdd(a + 0, w1 * m1.x); atomicAdd(a + 1, w1 * m1.y);
    atomicAdd(a + 2, w1 * m1.z); atomicAdd(a + 3, w1 * m1.w);
    a = accL + g2 * 4;
    atomicAdd(a + 0, w2 * m2.x); atomicAdd(a + 1, w2 * m2.y);
    atomicAdd(a + 2, w2 * m2.z); atomicAdd(a + 3, w2 * m2.w);
    a = accL + g3 * 4;
    atomicAdd(a + 0, w3 * m3.x); atomicAdd(a + 1, w3 * m3.y);
    atomicAdd(a + 2, w3 * m3.z); atomicAdd(a + 3, w3 * m3.w);
  }
  {
    unsigned done = q << 2;
    unsigned rem = n - done;
    if ((unsigned)t < rem) {
      u64 v = rp[done + t];
      unsigned lo = (unsigned)v, g = (unsigned)(v >> 32), s = lo >> 2;
      float w = dinvL[g * 4 + (lo & 3u)];
      float4 mm = dsi4[s];
      float* a = accL + g * 4;
      atomicAdd(a + 0, w * mm.x); atomicAdd(a + 1, w * mm.y);
      atomicAdd(a + 2, w * mm.z); atomicAdd(a + 3, w * mm.w);
    }
  }
  __syncthreads();
  // ---- epilogue: self-loops + fused MLP ----
  for (int gi = t; gi < GPBIN; gi += 512) {
    int g = bin * GPBIN + gi;
    if (g >= N_GRAPHS) break;
    float4 s0 = state4[4 * g + 0], s1 = state4[4 * g + 1];
    float4 s2 = state4[4 * g + 2], s3 = state4[4 * g + 3];
    float d0 = dinvL[gi * 4 + 0], d1 = dinvL[gi * 4 + 1];
    float d2 = dinvL[gi * 4 + 2], d3 = dinvL[gi * 4 + 3];
    float q0 = d0 * d0, q1 = d1 * d1, q2 = d2 * d2, q3 = d3 * d3;
    float ax = accL[gi * 4 + 0] + q0 * s0.x + q1 * s1.x + q2 * s2.x + q3 * s3.x;
    float ay = accL[gi * 4 + 1] + q0 * s0.y + q1 * s1.y + q2 * s2.y + q3 * s3.y;
    float az = accL[gi * 4 + 2] + q0 * s0.z + q1 * s1.z + q2 * s2.z + q3 * s3.z;
    float aw = accL[gi * 4 + 3] + q0 * s0.w + q1 * s1.w + q2 * s2.w + q3 * s3.w;
    float vx = s0.x + s1.x + s2.x + s3.x;
    float vy = s0.y + s1.y + s2.y + s3.y;
    float vz = s0.z + s1.z + s2.z + s3.z;
    float vw = s0.w + s1.w + s2.w + s3.w;
    float accum = b2[0];
#pragma unroll 4
    for (int j = 0; j < 32; ++j) {
      float4 wa = w1aT[j], wg = wg1T[j];
      float h = b1p[j]
              + vx * wa.x + vy * wa.y + vz * wa.z + vw * wa.w
              + ax * wg.x + ay * wg.y + az * wg.z + aw * wg.w;
      accum += fmaxf(h, 0.f) * w2s[j];
    }
    out[g] = accum;
  }
}

// ================= split fallback (bindeg + binreduce, round-7 proven) =================

__global__ __launch_bounds__(512) void bindeg_kernel(
    const u64* __restrict__ recs, const unsigned* __restrict__ gcur,
    const float4* __restrict__ state4,
    float* __restrict__ dinv, float4* __restrict__ dsi4) {
  __shared__ unsigned degL[NPBIN];
  int t = threadIdx.x, bin = blockIdx.x;
  for (int i = t; i < NPBIN; i += 512) degL[i] = 0;
  __syncthreads();
  unsigned n = gcur[bin]; if (n > BINCAP) n = BINCAP;
  const u64* rp = recs + (size_t)bin * BINCAP;
  const u64x2* rv = (const u64x2*)rp;
  unsigned nv = n >> 1;
  for (unsigned i = t; i < nv; i += 512) {
    u64x2 p = __builtin_nontemporal_load(rv + i);
    atomicAdd(&degL[((unsigned)(p.x >> 32)) * 4 + ((unsigned)p.x & 3u)], 1u);
    atomicAdd(&degL[((unsigned)(p.y >> 32)) * 4 + ((unsigned)p.y & 3u)], 1u);
  }
  if ((n & 1u) && t == 0) {
    u64 v = rp[n - 1];
    atomicAdd(&degL[((unsigned)(v >> 32)) * 4 + ((unsigned)v & 3u)], 1u);
  }
  __syncthreads();
  int nb = bin * NPBIN;
  for (int i = t; i < NPBIN; i += 512) {
    int node = nb + i;
    if (node < N_NODES) {
      float dv = rsqrtf((float)(degL[i] + 1u));
      dinv[node] = dv;
      float4 s = state4[node];
      dsi4[node] = make_float4(dv * s.x, dv * s.y, dv * s.z, dv * s.w);
    }
  }
}

__global__ __launch_bounds__(512, 8) void binreduce_kernel(
    const u64* __restrict__ recs, const unsigned* __restrict__ gcur,
    const float* __restrict__ dinv, const float4* __restrict__ dsi4,
    const float4* __restrict__ state4,
    const float* __restrict__ W1, const float* __restrict__ fold,
    const float* __restrict__ W2, const float* __restrict__ b2,
    float* __restrict__ out) {
  extern __shared__ float dynsm[];
  float* dinvL = dynsm;
  float* accL  = dynsm + NPBIN;
  __shared__ float4 w1aT[32], wg1T[32];
  __shared__ float b1p[32], w2s[32];
  int t = threadIdx.x, bin = blockIdx.x;
  if (t < 32) {
    w1aT[t] = make_float4(W1[t], W1[32 + t], W1[64 + t], W1[96 + t]);
    wg1T[t] = ((const float4*)fold)[t];
    b1p[t]  = fold[128 + t];
    w2s[t]  = W2[t];
  }
  int nb = bin * NPBIN;
  for (int i = t; i < NPBIN; i += 512) {
    int node = nb + i;
    dinvL[i] = (node < N_NODES) ? dinv[node] : 0.f;
    accL[i]  = 0.f;
  }
  __syncthreads();
  unsigned n = gcur[bin]; if (n > BINCAP) n = BINCAP;
  const u64* rp = recs + (size_t)bin * BINCAP;
  unsigned q = n >> 2;
  for (unsigned i = t; i < q; i += 512) {
    u64 r0 = __builtin_nontemporal_load(rp + i);
    u64 r1 = __builtin_nontemporal_load(rp + i + q);
    u64 r2 = __builtin_nontemporal_load(rp + i + 2 * q);
    u64 r3 = __builtin_nontemporal_load(rp + i + 3 * q);
    unsigned lo0 = (unsigned)r0, g0 = (unsigned)(r0 >> 32), s0 = lo0 >> 2;
    unsigned lo1 = (unsigned)r1, g1 = (unsigned)(r1 >> 32), s1 = lo1 >> 2;
    unsigned lo2 = (unsigned)r2, g2 = (unsigned)(r2 >> 32), s2 = lo2 >> 2;
    unsigned lo3 = (unsigned)r3, g3 = (unsigned)(r3 >> 32), s3 = lo3 >> 2;
    float w0 = dinvL[g0 * 4 + (lo0 & 3u)];
    float w1 = dinvL[g1 * 4 + (lo1 & 3u)];
    float w2 = dinvL[g2 * 4 + (lo2 & 3u)];
    float w3 = dinvL[g3 * 4 + (lo3 & 3u)];
    float4 m0 = dsi4[s0], m1 = dsi4[s1], m2 = dsi4[s2], m3 = dsi4[s3];
    float* a;
    a = accL + g0 * 4;
    atomicAdd(a + 0, w0 * m0.x); atomicAdd(a + 1, w0 * m0.y);
    atomicAdd(a + 2, w0 * m0.z); atomicAdd(a + 3, w0 * m0.w);
    a = accL + g1 * 4;
    atomicAdd(a + 0, w1 * m1.x); atomicAdd(a + 1, w1 * m1.y);
    atomicAdd(a + 2, w1 * m1.z); atomicAdd(a + 3, w1 * m1.w);
    a = accL + g2 * 4;
    atomicAdd(a + 0, w2 * m2.x); atomicAdd(a + 1, w2 * m2.y);
    atomicAdd(a + 2, w2 * m2.z); atomicAdd(a + 3, w2 * m2.w);
    a = accL + g3 * 4;
    atomicAdd(a + 0, w3 * m3.x); atomicAdd(a + 1, w3 * m3.y);
    atomicAdd(a + 2, w3 * m3.z); atomicAdd(a + 3, w3 * m3.w);
  }
  unsigned done = q << 2;
  unsigned rem = n - done;
  if ((unsigned)t < rem) {
    u64 v = rp[done + t];
    unsigned lo = (unsigned)v, g = (unsigned)(v >> 32), s = lo >> 2;
    float w = dinvL[g * 4 + (lo & 3u)];
    float4 mm = dsi4[s];
    float* a = accL + g * 4;
    atomicAdd(a + 0, w * mm.x); atomicAdd(a + 1, w * mm.y);
    atomicAdd(a + 2, w * mm.z); atomicAdd(a + 3, w * mm.w);
  }
  __syncthreads();
  for (int gi = t; gi < GPBIN; gi += 512) {
    int g = bin * GPBIN + gi;
    if (g >= N_GRAPHS) break;
    float4 s0 = state4[4 * g + 0], s1 = state4[4 * g + 1];
    float4 s2 = state4[4 * g + 2], s3 = state4[4 * g + 3];
    float d0 = dinvL[gi * 4 + 0], d1 = dinvL[gi * 4 + 1];
    float d2 = dinvL[gi * 4 + 2], d3 = dinvL[gi * 4 + 3];
    float q0 = d0 * d0, q1 = d1 * d1, q2 = d2 * d2, q3 = d3 * d3;
    float ax = accL[gi * 4 + 0] + q0 * s0.x + q1 * s1.x + q2 * s2.x + q3 * s3.x;
    float ay = accL[gi * 4 + 1] + q0 * s0.y + q1 * s1.y + q2 * s2.y + q3 * s3.y;
    float az = accL[gi * 4 + 2] + q0 * s0.z + q1 * s1.z + q2 * s2.z + q3 * s3.z;
    float aw = accL[gi * 4 + 3] + q0 * s0.w + q1 * s1.w + q2 * s2.w + q3 * s3.w;
    float vx = s0.x + s1.x + s2.x + s3.x;
    float vy = s0.y + s1.y + s2.y + s3.y;
    float vz = s0.z + s1.z + s2.z + s3.z;
    float vw = s0.w + s1.w + s2.w + s3.w;
    float accum = b2[0];
#pragma unroll 4
    for (int j = 0; j < 32; ++j) {
      float4 wa = w1aT[j], wg = wg1T[j];
      float h = b1p[j]
              + vx * wa.x + vy * wa.y + vz * wa.z + vw * wa.w
              + ax * wg.x + ay * wg.y + az * wg.z + aw * wg.w;
      accum += fmaxf(h, 0.f) * w2s[j];
    }
    out[g] = accum;
  }
}

// ================= round-3 emergency fallback =================

__global__ __launch_bounds__(256) void deg_kernel(
    const i32x4* __restrict__ dst4, unsigned* __restrict__ deg) {
  int stride = gridDim.x * blockDim.x;
  for (int e = blockIdx.x * blockDim.x + threadIdx.x; e < N_EDGES / 4; e += stride) {
    i32x4 d = __builtin_nontemporal_load(dst4 + e);
    atomicAdd(&deg[d.x], 1u); atomicAdd(&deg[d.y], 1u);
    atomicAdd(&deg[d.z], 1u); atomicAdd(&deg[d.w], 1u);
  }
}

__global__ __launch_bounds__(256) void dinv_kernel(unsigned* __restrict__ degdinv) {
  int i = blockIdx.x * blockDim.x + threadIdx.x;
  if (i < N_NODES) {
    float dv = rsqrtf((float)(degdinv[i] + 1u));
    reinterpret_cast<float*>(degdinv)[i] = dv;
  }
}

__global__ __launch_bounds__(256) void scatter_kernel(
    const i32x4* __restrict__ src4, const i32x4* __restrict__ dst4,
    const float* __restrict__ dinv, const float4* __restrict__ state4,
    float* __restrict__ acc) {
  int stride = gridDim.x * blockDim.x;
  for (int e = blockIdx.x * blockDim.x + threadIdx.x; e < N_EDGES / 4; e += stride) {
    i32x4 s4 = __builtin_nontemporal_load(src4 + e);
    i32x4 d4 = __builtin_nontemporal_load(dst4 + e);
#pragma unroll
    for (int u = 0; u < 4; ++u) {
      int s = (u == 0) ? s4.x : (u == 1) ? s4.y : (u == 2) ? s4.z : s4.w;
      int d = (u == 0) ? d4.x : (u == 1) ? d4.y : (u == 2) ? d4.z : d4.w;
      float w = dinv[s] * dinv[d];
      float4 st = state4[s];
      float* base = acc + (size_t)(d >> 2) * 4;
      atomicAdd(base + 0, w * st.x); atomicAdd(base + 1, w * st.y);
      atomicAdd(base + 2, w * st.z); atomicAdd(base + 3, w * st.w);
    }
  }
}

__global__ __launch_bounds__(256) void final_kernel(
    const float4* __restrict__ state4, const float4* __restrict__ dinv4,
    const float4* __restrict__ acc4, const float* __restrict__ W1,
    const float* __restrict__ fold, const float* __restrict__ W2,
    const float* __restrict__ b2, float* __restrict__ out) {
  __shared__ float4 w1aT[32], wg1T[32];
  __shared__ float b1p[32], w2s[32];
  int t = threadIdx.x;
  if (t < 32) {
    w1aT[t] = make_float4(W1[t], W1[32 + t], W1[64 + t], W1[96 + t]);
    wg1T[t] = ((const float4*)fold)[t];
    b1p[t]  = fold[128 + t];
    w2s[t]  = W2[t];
  }
  __syncthreads();
  int b = blockIdx.x * blockDim.x + t;
  if (b >= N_GRAPHS) return;
  float4 s0 = state4[4 * b + 0], s1 = state4[4 * b + 1];
  float4 s2 = state4[4 * b + 2], s3 = state4[4 * b + 3];
  float4 dv = dinv4[b];
  float4 a  = acc4[b];
  float q0 = dv.x * dv.x, q1 = dv.y * dv.y, q2 = dv.z * dv.z, q3 = dv.w * dv.w;
  a.x += q0 * s0.x + q1 * s1.x + q2 * s2.x + q3 * s3.x;
  a.y += q0 * s0.y + q1 * s1.y + q2 * s2.y + q3 * s3.y;
  a.z += q0 * s0.z + q1 * s1.z + q2 * s2.z + q3 * s3.z;
  a.w += q0 * s0.w + q1 * s1.w + q2 * s2.w + q3 * s3.w;
  float4 vs;
  vs.x = s0.x + s1.x + s2.x + s3.x;
  vs.y = s0.y + s1.y + s2.y + s3.y;
  vs.z = s0.z + s1.z + s2.z + s3.z;
  vs.w = s0.w + s1.w + s2.w + s3.w;
  float accum = b2[0];
#pragma unroll
  for (int j = 0; j < 32; ++j) {
    float4 wa = w1aT[j], wg = wg1T[j];
    float h = b1p[j]
            + vs.x * wa.x + vs.y * wa.y + vs.z * wa.z + vs.w * wa.w
            + a.x * wg.x + a.y * wg.y + a.z * wg.z + a.w * wg.w;
    accum += fmaxf(h, 0.f) * w2s[j];
  }
  out[b] = accum;
}

// ================= launch =================

extern "C" void kernel_launch(void* const* d_in, const int* in_sizes, int n_in,
                              void* d_out, int out_size, void* d_ws, size_t ws_size,
                              hipStream_t stream) {
  const float* state = (const float*)d_in[0];
  const int*   ei    = (const int*)d_in[1];   // int32: [2][N_EDGES]
  const float* Wgcn  = (const float*)d_in[2];
  const float* bgcn  = (const float*)d_in[3];
  const float* W1    = (const float*)d_in[4];
  const float* b1    = (const float*)d_in[5];
  const float* W2    = (const float*)d_in[6];
  const float* b2    = (const float*)d_in[7];
  float* out = (float*)d_out;

  char* ws = (char*)d_ws;
  const size_t MB = 1024u * 1024u;

  const size_t recs_bytes = (size_t)NBIN * BINCAP * 8;            // 112,050,176
  const size_t dinv_off   = recs_bytes;                            // 16 MB (split path)
  const size_t dsi_off    = dinv_off + (size_t)N_NODES * 4;        // 16B-aligned
  const size_t gcur_off   = (dsi_off + (size_t)N_NODES * 16 + 255) & ~(size_t)255;
  const size_t need_bin   = gcur_off + 8192 + 1024;                // ~192 MB

  const size_t scat_smem = (size_t)NBIN * LCAP * 8 + NBIN * 4;     // 128,964 B
  const size_t red_smem  = 2 * NPBIN * 4;                          // 32 KiB

  if (ws_size >= need_bin) {
    const u64*      recs = (const u64*)ws;
    u64*            recsw = (u64*)ws;
    float*          dinv = (float*)(ws + dinv_off);
    float4*         dsi4 = (float4*)(ws + dsi_off);
    unsigned*       gcur = (unsigned*)(ws + gcur_off);
    float*          fold = (float*)(ws + gcur_off + 8192);
    const float4*   state4 = (const float4*)state;

    (void)hipMemsetAsync(gcur, 0, 8192, stream);
    fold_kernel<<<1, 128, 0, stream>>>(Wgcn, bgcn, W1, b1, fold);
    binscatter_kernel<<<SBLOCKS, 512, scat_smem, stream>>>(
        ei, ei + N_EDGES, gcur, recsw);

    // try cooperative fused path
    bool coop_ok = false;
    {
      int dev = 0;
      (void)hipGetDevice(&dev);
      int coop_attr = 0;
      (void)hipDeviceGetAttribute(&coop_attr, hipDeviceAttributeCooperativeLaunch, dev);
      int numCU = 0;
      (void)hipDeviceGetAttribute(&numCU, hipDeviceAttributeMultiprocessorCount, dev);
      int maxblk = 0;
      hipError_t oe = hipOccupancyMaxActiveBlocksPerMultiprocessor(
          &maxblk, fusedreduce_kernel, 512, red_smem);
      if (coop_attr && oe == hipSuccess && (long)maxblk * numCU >= NBIN) {
        const float* W1p = W1; const float* foldp = fold;
        const float* W2p = W2; const float* b2p = b2;
        void* args[] = {(void*)&recs, (void*)&gcur, (void*)&dsi4, (void*)&state4,
                        (void*)&W1p, (void*)&foldp, (void*)&W2p, (void*)&b2p,
                        (void*)&out};
        hipError_t le = hipLaunchCooperativeKernel(
            fusedreduce_kernel, dim3(NBIN), dim3(512), args,
            (unsigned)red_smem, stream);
        coop_ok = (le == hipSuccess);
      }
    }
    if (!coop_ok) {
      bindeg_kernel<<<NBIN, 512, 0, stream>>>(recs, gcur, state4, dinv, dsi4);
      binreduce_kernel<<<NBIN, 512, red_smem, stream>>>(
          recs, gcur, dinv, dsi4, state4, W1, fold, W2, b2, out);
    }
    return;
  }

  // emergency fallback (33 MB): round-3 atomic-scatter path
  {
    unsigned* deg  = (unsigned*)ws;
    float*    acc  = (float*)(ws + 16 * MB);
    float*    fold = (float*)(ws + 32 * MB);
    (void)hipMemsetAsync(d_ws, 0, 32 * MB + 1024, stream);
    fold_kernel<<<1, 128, 0, stream>>>(Wgcn, bgcn, W1, b1, fold);
    deg_kernel<<<4096, 256, 0, stream>>>((const i32x4*)(ei + N_EDGES), deg);
    dinv_kernel<<<(N_NODES + 255) / 256, 256, 0, stream>>>(deg);
    scatter_kernel<<<8192, 256, 0, stream>>>(
        (const i32x4*)ei, (const i32x4*)(ei + N_EDGES),
        (const float*)deg, (const float4*)state, acc);
    final_kernel<<<(N_GRAPHS + 255) / 256, 256, 0, stream>>>(
        (const float4*)state, (const float4*)deg, (const float4*)acc,
        W1, fold, W2, b2, out);
  }
}